// Round 3
// baseline (916.757 us; speedup 1.0000x reference)
//
#include <hip/hip_runtime.h>

// SparseLinearAttention: B=1, L=4096, H=16, D=64, BLKQ=BLKK=64, M=N=64, T=8.
// fp32 I/O. SINGLE dispatch: every block preps (h, n=m) then flags; m<4
// blocks reduce kvp+apply W (m2), m==4 reduces ksum; all blocks then run
// topk + block-sparse + linear attention. Per-head flag handoff (u64
// double-magic, device-scope atomics; all 1024 blocks co-resident at
// 5 blk/CU so spins are deadlock-free, with bounded caps).

#define NH   16
#define DH   64
#define NBLK 64
#define TSEL 8

typedef unsigned short u16;
typedef unsigned int   u32;
typedef unsigned long long u64;
typedef __attribute__((ext_vector_type(8))) short short8;  // 8 bf16
typedef __attribute__((ext_vector_type(4))) float f4;
typedef __attribute__((ext_vector_type(4))) u32 u32x4;

#define MFMA_BF16(a, b, c) __builtin_amdgcn_mfma_f32_16x16x32_bf16(a, b, c, 0, 0, 0)
#define MAGIC64 0x2468ACE013579BDFull
#define SPIN_CAP 1000000

__device__ __forceinline__ u16 f2bf_rne(float f) {
  u32 u = __float_as_uint(f);
  u += 0x7fffu + ((u >> 16) & 1u);
  return (u16)(u >> 16);
}
__device__ __forceinline__ u32 pk2(float a, float b) {
  return (u32)f2bf_rne(a) | ((u32)f2bf_rne(b) << 16);
}
__device__ __forceinline__ float bf2f(u16 u) { return __uint_as_float(((u32)u) << 16); }

// 8-bf16 fragment from a swizzled row-major bf16 tile (128B rows; logical
// 16B block j of row r stored at j^(r&7)).
__device__ __forceinline__ short8 frag_row(const u16* t, int row, int jblk) {
  return *(const short8*)((const char*)t + row * 128 + ((jblk ^ (row & 7)) * 16));
}

// LDS map (27904 B total), phase-sequenced:
//   [0,8192)      vsl (prep V^T)  -> km_s lo -> K-tile -> m2_l
//   [8192,24832)  kcol 64x65 f32 (kfm 8K overlays @8192 from stage C)
//                 -> km_s hi + qmp@16640 + qmf@17664 (+ producer wl@0,
//                    red16@17920) -> V-tile@8192 + P@16384 -> ks/bias@8192
//   [24832,27904) redmx(/ksred) | redsm | kmred
__global__ __launch_bounds__(256, 5) void mega_kernel(
    const float* __restrict__ q, const float* __restrict__ k,
    const float* __restrict__ v, const float* __restrict__ wgt,
    const float* __restrict__ bproj,
    u16* __restrict__ kT, u16* __restrict__ vT,
    float* __restrict__ kvp, float* __restrict__ ksp,
    float* __restrict__ kmv, u16* __restrict__ m2t,
    float* __restrict__ ksum, u64* __restrict__ pf, u64* __restrict__ mf,
    float* __restrict__ out) {
  __shared__ __align__(16) char smem[27904];
  int b = blockIdx.x;
  int m = (b >> 3) & 63;
  int h = 2 * (b & 7) + (b >> 9);
  int tid = threadIdx.x, w = tid >> 6, lane = tid & 63;
  int lq = lane & 15, quad = lane >> 4;

  char* vsl = smem;
  char* kfm = smem + 8192;
  float* kcol = (float*)(smem + 8192);
  float* redmx = (float*)(smem + 24832);
  float* redsm = (float*)(smem + 25856);
  float* kmred = (float*)(smem + 26880);
  float* ksred = redmx;   // union: redmx dead after stage B

  // ================= PHASE 1: prep for (h, n=m) =================
  {
    int n = m;
    int row = lane, qd = w;
    float kv[16];
    {
      const float* kr = k + (size_t)(n * 64 + row) * 1024 + h * 64 + qd * 16;
#pragma unroll
      for (int c4 = 0; c4 < 4; c4++) {
        float4 a = *(const float4*)(kr + c4 * 4);
        kv[c4 * 4] = a.x; kv[c4 * 4 + 1] = a.y; kv[c4 * 4 + 2] = a.z; kv[c4 * 4 + 3] = a.w;
      }
    }
    { // kT global write (raw bf16, swizzled row layout)
      char* ktb = (char*)(kT + ((size_t)(h * 64 + n)) * 4096);
      uint4 w0 = make_uint4(pk2(kv[0], kv[1]), pk2(kv[2], kv[3]),
                            pk2(kv[4], kv[5]), pk2(kv[6], kv[7]));
      uint4 w1 = make_uint4(pk2(kv[8], kv[9]), pk2(kv[10], kv[11]),
                            pk2(kv[12], kv[13]), pk2(kv[14], kv[15]));
      *(uint4*)(ktb + row * 128 + (((2 * qd) ^ (row & 7)) * 16)) = w0;
      *(uint4*)(ktb + row * 128 + (((2 * qd + 1) ^ (row & 7)) * 16)) = w1;
    }
    { // raw K into column-major LDS (km)
#pragma unroll
      for (int j = 0; j < 16; j++) kcol[(qd * 16 + j) * 65 + row] = kv[j];
    }
    { // V^T into LDS
      const float* vr = v + (size_t)(n * 64 + row) * 1024 + h * 64 + qd * 16;
      int kb = row >> 3, klo = row & 7;
#pragma unroll
      for (int c4 = 0; c4 < 4; c4++) {
        float4 a = *(const float4*)(vr + c4 * 4);
        float vv[4] = {a.x, a.y, a.z, a.w};
#pragma unroll
        for (int jj = 0; jj < 4; jj++) {
          int e = qd * 16 + c4 * 4 + jj;
          *(u16*)(vsl + e * 128 + ((kb ^ (e & 7)) * 16) + klo * 2) = f2bf_rne(vv[jj]);
        }
      }
    }
    { // row max partial
      float mx = kv[0];
#pragma unroll
      for (int j = 1; j < 16; j++) mx = fmaxf(mx, kv[j]);
      redmx[qd * 64 + row] = mx;
    }
    __syncthreads();
    { // km partials
      int c = tid & 63, g = tid >> 6;
      float pk = 0.f;
#pragma unroll
      for (int i = 0; i < 16; i++) pk += kcol[c * 65 + g * 16 + i];
      kmred[g * 64 + c] = pk;
    }
    { // row softmax: max fold + exp + sum partial
      float mx = fmaxf(fmaxf(redmx[row], redmx[64 + row]),
                       fmaxf(redmx[128 + row], redmx[192 + row]));
      float sm = 0.f;
#pragma unroll
      for (int j = 0; j < 16; j++) { kv[j] = __expf(kv[j] - mx); sm += kv[j]; }
      redsm[qd * 64 + row] = sm;
    }
    __syncthreads();
    if (tid < 64)
      kmv[h * 4096 + n * 64 + tid] =
          (kmred[tid] + kmred[64 + tid] + kmred[128 + tid] + kmred[192 + tid]) * (1.0f / 64.0f);
    {
      float sm = redsm[row] + redsm[64 + row] + redsm[128 + row] + redsm[192 + row];
      float inv = 1.0f / sm;
      int rb = row >> 3, rlo = row & 7;
#pragma unroll
      for (int j = 0; j < 16; j++) {
        int d = qd * 16 + j;
        *(u16*)(kfm + d * 128 + (((rb) ^ (d & 7)) * 16) + rlo * 2) = f2bf_rne(kv[j] * inv);
      }
    }
    __syncthreads();   // kfm + vsl complete

    { // vT global copy
      uint4* vt_out = (uint4*)(vT + ((size_t)(h * 64 + n)) * 4096);
      vt_out[tid] = ((const uint4*)vsl)[tid];
      vt_out[256 + tid] = ((const uint4*)vsl)[256 + tid];
    }
    { // ksum partial
      float ks = 0.f;
      short8 x0 = frag_row((const u16*)kfm, lane, 2 * w);
      short8 x1 = frag_row((const u16*)kfm, lane, 2 * w + 1);
#pragma unroll
      for (int e = 0; e < 8; e++) ks += bf2f((u16)x0[e]) + bf2f((u16)x1[e]);
      ksred[tid] = ks;
    }
    { // kvsum MFMA partial -> plain global store
      f4 acc[4];
      f4 zz = {0.f, 0.f, 0.f, 0.f};
#pragma unroll
      for (int et = 0; et < 4; et++) acc[et] = zz;
#pragma unroll
      for (int ks2 = 0; ks2 < 2; ks2++) {
        short8 a_ = frag_row((const u16*)kfm, w * 16 + lq, 4 * ks2 + quad);
#pragma unroll
        for (int et = 0; et < 4; et++)
          acc[et] = MFMA_BF16(a_, frag_row((const u16*)vsl, et * 16 + lq, 4 * ks2 + quad), acc[et]);
      }
      float* kvb = kvp + ((size_t)(h * 64 + n)) * 4096;
#pragma unroll
      for (int r = 0; r < 4; r++)
#pragma unroll
        for (int et = 0; et < 4; et++)
          kvb[(w * 16 + quad * 4 + r) * 64 + et * 16 + lq] = acc[et][r];
    }
    __syncthreads();
    if (tid < 64)
      ksp[((size_t)(h * 64 + n)) * 64 + tid] = ksred[tid] + ksred[64 + tid] +
                                               ksred[128 + tid] + ksred[192 + tid];
    // release prep flag
    __threadfence();
    __syncthreads();
    if (tid == 0)
      __hip_atomic_store(pf + h * 64 + n, MAGIC64, __ATOMIC_RELEASE,
                         __HIP_MEMORY_SCOPE_AGENT);
  }

  // ======= PHASE 2: q-mean partials (no deps — hides the spin) =======
  float* qmp = (float*)(smem + 16640);
  float* qmf = (float*)(smem + 17664);
  {
    int c = tid & 63, g = tid >> 6;
    const float* qcol = q + ((size_t)(m * 64 + g * 16)) * 1024 + h * 64 + c;
    float qp = 0.f;
#pragma unroll
    for (int i = 0; i < 16; i++) qp += qcol[(size_t)i * 1024];
    qmp[g * 64 + c] = qp;
  }

  // ======= PHASE 3: wait for all 64 preps of this head =======
  if (tid < 64) {
    const u64* fp0 = pf + h * 64 + tid;
    int c = 0;
    while (__hip_atomic_load(fp0, __ATOMIC_ACQUIRE, __HIP_MEMORY_SCOPE_AGENT) != MAGIC64) {
      if (++c > SPIN_CAP) break;
      __builtin_amdgcn_s_sleep(4);
    }
  }
  __syncthreads();

  // ======= PHASE 4: producers — m<4: m2 slice; m==4: ksum =======
  if (m < 4) {
    float* wl = (float*)smem;              // 64*65 f32 = 16640 B
    float* red16 = (float*)(smem + 17920); // 16*64 f32
    int j = tid & 63, rr = tid >> 6;
#pragma unroll
    for (int i = 0; i < 16; i++) {
      int f = i * 256 + tid;
      wl[(f >> 6) * 65 + (f & 63)] = wgt[f];
    }
#pragma unroll
    for (int s = 0; s < 4; s++) {
      int d = m * 16 + rr * 4 + s;
      const float* base = kvp + (size_t)h * 64 * 4096 + d * 64 + j;
      float s0 = 0.f, s1 = 0.f, s2 = 0.f, s3 = 0.f;
#pragma unroll
      for (int n4 = 0; n4 < 16; n4++) {
        s0 += base[(size_t)(n4 * 4 + 0) * 4096];
        s1 += base[(size_t)(n4 * 4 + 1) * 4096];
        s2 += base[(size_t)(n4 * 4 + 2) * 4096];
        s3 += base[(size_t)(n4 * 4 + 3) * 4096];
      }
      red16[(rr * 4 + s) * 64 + j] = (s0 + s1) + (s2 + s3);
    }
    __syncthreads();
    int e = tid & 63, rr2 = tid >> 6;
#pragma unroll
    for (int s = 0; s < 4; s++) {
      int dloc = rr2 * 4 + s;
      float acc = 0.f;
#pragma unroll
      for (int jj = 0; jj < 64; jj++) acc = fmaf(red16[dloc * 64 + jj], wl[e * 65 + jj], acc);
      int d = m * 16 + dloc;
      *(u16*)((char*)m2t + (size_t)h * 8192 + e * 128 +
              (((d >> 3) ^ (e & 7)) * 16) + (d & 7) * 2) = f2bf_rne(acc);
    }
  } else if (m == 4) {
    if (tid < 64) {
      const float* base = ksp + (size_t)h * 64 * 64 + tid;
      float s = 0.f;
#pragma unroll
      for (int n = 0; n < 64; n++) s += base[(size_t)n * 64];
      ksum[h * 64 + tid] = s;
    }
  }
  if (m < 5) {
    __threadfence();
    __syncthreads();
    if (tid == 0)
      __hip_atomic_store(mf + h * 5 + m, MAGIC64, __ATOMIC_RELEASE,
                         __HIP_MEMORY_SCOPE_AGENT);
    __syncthreads();   // wl/red16 regions free for km_s
  }

  // ======= PHASE 5: topk (q-block mean vs km, butterfly top-8) =======
  float* km_s = (float*)smem;
  {
#pragma unroll
    for (int i = 0; i < 16; i++) {
      int idx = i * 256 + tid;
      km_s[(idx >> 6) * 65 + (idx & 63)] = kmv[h * 4096 + idx];
    }
  }
  __syncthreads();
  if (tid < 64) qmf[tid] = qmp[tid] + qmp[64 + tid] + qmp[128 + tid] + qmp[192 + tid];
  __syncthreads();
  int blks[8];
  {
    int n = lane;
    float s = 0.f;
#pragma unroll
    for (int d = 0; d < 64; d++) s += qmf[d] * km_s[n * 65 + d];
    float my = s;
#pragma unroll
    for (int t = 0; t < TSEL; t++) {
      float vv = my; int idx = n;
#pragma unroll
      for (int off = 1; off < 64; off <<= 1) {
        float ov = __shfl_xor(vv, off);
        int oi = __shfl_xor(idx, off);
        if (ov > vv || (ov == vv && oi < idx)) { vv = ov; idx = oi; }
      }
      int sel = __builtin_amdgcn_readfirstlane(idx);
      blks[t] = sel;
      if (n == sel) my = -INFINITY;
    }
  }
  __syncthreads();   // km_s dead

  // ======= PHASE 6: block-sparse attention K-loop =======
  char* buf = smem;
  char* p_b = smem + 16384 + w * 2048;
  const int qrow = w * 16 + lq;
  const float* qr_g = q + ((size_t)(m * 64 + qrow)) * 1024 + h * 64;
  short8 qf[2];
#pragma unroll
  for (int ks = 0; ks < 2; ks++) {
    const float* gp = qr_g + (4 * ks + quad) * 8;
    float4 a = *(const float4*)gp;
    float4 bb = *(const float4*)(gp + 4);
    u32x4 tt = {pk2(a.x, a.y), pk2(a.z, a.w), pk2(bb.x, bb.y), pk2(bb.z, bb.w)};
    qf[ks] = __builtin_bit_cast(short8, tt);
  }

  { // stage K/V block 0
    const uint4* kt0 = (const uint4*)(kT + ((size_t)(h * 64 + blks[0])) * 4096);
    const uint4* vt0 = (const uint4*)(vT + ((size_t)(h * 64 + blks[0])) * 4096);
    ((uint4*)buf)[tid] = kt0[tid];
    ((uint4*)buf)[256 + tid] = kt0[256 + tid];
    ((uint4*)(buf + 8192))[tid] = vt0[tid];
    ((uint4*)(buf + 8192))[256 + tid] = vt0[256 + tid];
  }
  __syncthreads();

  float mrun = -INFINITY, lrun = 0.f;
  f4 o[4];
  f4 zz = {0.f, 0.f, 0.f, 0.f};
#pragma unroll
  for (int et = 0; et < 4; et++) o[et] = zz;

  const u16* kc = (const u16*)buf;
  const u16* vc = (const u16*)(buf + 8192);

  for (int t = 0; t < 8; t++) {
    uint4 pk0, pk1, pv0, pv1;
    if (t < 7) {
      const uint4* ktn = (const uint4*)(kT + ((size_t)(h * 64 + blks[t + 1])) * 4096);
      const uint4* vtn = (const uint4*)(vT + ((size_t)(h * 64 + blks[t + 1])) * 4096);
      pk0 = ktn[tid]; pk1 = ktn[256 + tid];
      pv0 = vtn[tid]; pv1 = vtn[256 + tid];
    }

    // S^T = K·Q^T
    f4 s[4];
#pragma unroll
    for (int kt = 0; kt < 4; kt++) s[kt] = zz;
    __builtin_amdgcn_s_setprio(1);
#pragma unroll
    for (int ks = 0; ks < 2; ks++)
#pragma unroll
      for (int kt = 0; kt < 4; kt++)
        s[kt] = MFMA_BF16(frag_row(kc, kt * 16 + lq, 4 * ks + quad), qf[ks], s[kt]);
    __builtin_amdgcn_s_setprio(0);

    // online softmax (16 scores/lane)
    float mp = -INFINITY;
#pragma unroll
    for (int kt = 0; kt < 4; kt++)
#pragma unroll
      for (int r = 0; r < 4; r++) mp = fmaxf(mp, s[kt][r]);
    mp = fmaxf(mp, __shfl_xor(mp, 16));
    mp = fmaxf(mp, __shfl_xor(mp, 32));
    mp *= 0.125f;
    if (__any(mp > mrun)) {
      float mn = fmaxf(mrun, mp);
      float al = __expf(mrun - mn);
      mrun = mn;
      lrun *= al;
#pragma unroll
      for (int et = 0; et < 4; et++)
#pragma unroll
        for (int r = 0; r < 4; r++) o[et][r] *= al;
    }
    float rs_ = 0.f;
#pragma unroll
    for (int kt = 0; kt < 4; kt++) {
      float p0 = __expf(fmaf(s[kt][0], 0.125f, -mrun));
      float p1 = __expf(fmaf(s[kt][1], 0.125f, -mrun));
      float p2 = __expf(fmaf(s[kt][2], 0.125f, -mrun));
      float p3 = __expf(fmaf(s[kt][3], 0.125f, -mrun));
      rs_ += p0 + p1 + p2 + p3;
      u32 lo32 = (__float_as_uint(p0) >> 16) | (__float_as_uint(p1) & 0xffff0000u);
      u32 hi32 = (__float_as_uint(p2) >> 16) | (__float_as_uint(p3) & 0xffff0000u);
      int addr = lq * 128 + (((kt * 2 + (quad >> 1)) ^ (lq & 7)) * 16) + (quad & 1) * 8;
      *(uint2*)(p_b + addr) = make_uint2(lo32, hi32);
    }
    rs_ += __shfl_xor(rs_, 16);
    rs_ += __shfl_xor(rs_, 32);
    lrun += rs_;

    // O^T += V^T · P^T
    __builtin_amdgcn_s_setprio(1);
#pragma unroll
    for (int ks = 0; ks < 2; ks++) {
      short8 pfr = frag_row((const u16*)p_b, lq, 4 * ks + quad);
#pragma unroll
      for (int et = 0; et < 4; et++)
        o[et] = MFMA_BF16(frag_row(vc, et * 16 + lq, 4 * ks + quad), pfr, o[et]);
    }
    __builtin_amdgcn_s_setprio(0);

    if (t < 7) {
      __syncthreads();
      ((uint4*)buf)[tid] = pk0;
      ((uint4*)buf)[256 + tid] = pk1;
      ((uint4*)(buf + 8192))[tid] = pv0;
      ((uint4*)(buf + 8192))[256 + tid] = pv1;
      __syncthreads();
    }
  }

  // ======= PHASE 7: linear attention (needs m2/ksum flags) =======
  __syncthreads();
  if (tid < 5) {
    const u64* fp1 = mf + h * 5 + tid;
    int c = 0;
    while (__hip_atomic_load(fp1, __ATOMIC_ACQUIRE, __HIP_MEMORY_SCOPE_AGENT) != MAGIC64) {
      if (++c > SPIN_CAP) break;
      __builtin_amdgcn_s_sleep(4);
    }
  }
  __syncthreads();
  {
    const uint4* src = (const uint4*)((const char*)m2t + (size_t)h * 8192);
    ((uint4*)buf)[tid] = src[tid];
    ((uint4*)buf)[256 + tid] = src[256 + tid];
    if (tid < 64) {
      ((float*)(buf + 8192))[tid] = ksum[h * 64 + tid];
      ((float*)(buf + 8448))[tid] = bproj[tid];
    }
  }
  __syncthreads();
  u16* m2_l = (u16*)buf;
  float* ks_s = (float*)(buf + 8192);
  float* b_s = (float*)(buf + 8448);

  float ev[16];
  float mx = -INFINITY;
#pragma unroll
  for (int c4 = 0; c4 < 4; c4++) {
    float4 a = *(const float4*)(qr_g + quad * 16 + c4 * 4);
    ev[c4 * 4] = a.x; ev[c4 * 4 + 1] = a.y; ev[c4 * 4 + 2] = a.z; ev[c4 * 4 + 3] = a.w;
    mx = fmaxf(mx, fmaxf(fmaxf(a.x, a.y), fmaxf(a.z, a.w)));
  }
  mx = fmaxf(mx, __shfl_xor(mx, 16));
  mx = fmaxf(mx, __shfl_xor(mx, 32));
  float sum = 0.f, eks = 0.f;
#pragma unroll
  for (int j = 0; j < 16; j++) {
    float e = __expf(ev[j] - mx);
    ev[j] = e;
    sum += e;
    eks += e * ks_s[quad * 16 + j];
  }
  sum += __shfl_xor(sum, 16); sum += __shfl_xor(sum, 32);
  eks += __shfl_xor(eks, 16); eks += __shfl_xor(eks, 32);
  float invs = 1.0f / sum;
  float den = fmaf(eks, invs, 1e-6f);
  float scale = invs / den;
  uint4 e0v = make_uint4(pk2(ev[0], ev[1]), pk2(ev[2], ev[3]),
                         pk2(ev[4], ev[5]), pk2(ev[6], ev[7]));
  uint4 e1v = make_uint4(pk2(ev[8], ev[9]), pk2(ev[10], ev[11]),
                         pk2(ev[12], ev[13]), pk2(ev[14], ev[15]));
  *(uint4*)(p_b + lq * 128 + (((2 * quad) ^ (lq & 7)) * 16)) = e0v;
  *(uint4*)(p_b + lq * 128 + (((2 * quad + 1) ^ (lq & 7)) * 16)) = e1v;

  f4 oc[4];
  f4 zz2 = {0.f, 0.f, 0.f, 0.f};
#pragma unroll
  for (int et = 0; et < 4; et++) oc[et] = zz2;
  __builtin_amdgcn_s_setprio(1);
#pragma unroll
  for (int ks2 = 0; ks2 < 2; ks2++) {
    short8 ef = frag_row((const u16*)p_b, lq, 4 * ks2 + quad);
#pragma unroll
    for (int et = 0; et < 4; et++)
      oc[et] = MFMA_BF16(frag_row(m2_l, et * 16 + lq, 4 * ks2 + quad), ef, oc[et]);
  }
  __builtin_amdgcn_s_setprio(0);

  // ---- single write: out = o_s/l + o_l*scale + bias ----
  float invl = 1.0f / lrun;
  float* gp = out + ((size_t)(m * 64 + qrow)) * 1024 + h * 64 + quad * 4;
#pragma unroll
  for (int et = 0; et < 4; et++) {
    int e0 = et * 16 + quad * 4;
    float4 ov;
    ov.x = o[et][0] * invl + oc[et][0] * scale + b_s[e0 + 0];
    ov.y = o[et][1] * invl + oc[et][1] * scale + b_s[e0 + 1];
    ov.z = o[et][2] * invl + oc[et][2] * scale + b_s[e0 + 2];
    ov.w = o[et][3] * invl + oc[et][3] * scale + b_s[e0 + 3];
    *(float4*)(gp + et * 16) = ov;
  }
}

extern "C" void kernel_launch(void* const* d_in, const int* in_sizes, int n_in,
                              void* d_out, int out_size, void* d_ws, size_t ws_size,
                              hipStream_t stream) {
  const float* q = (const float*)d_in[0];
  const float* k = (const float*)d_in[1];
  const float* v = (const float*)d_in[2];
  const float* w = (const float*)d_in[3];
  const float* b = (const float*)d_in[4];
  float* out = (float*)d_out;

  // ws: kT 8MB u16 | vT 8MB u16 | kvp 16MB f32 | ksp 256KB f32 |
  //     kmv 256KB f32 | ksum 4KB f32 | m2t 128KB u16 | pf 8KB u64 | mf 640B
  u16* kT = (u16*)d_ws;
  u16* vT = kT + 4194304;
  float* kvp = (float*)(vT + 4194304);
  float* ksp = kvp + 4194304;
  float* kmv = ksp + 65536;
  float* ksum = kmv + 65536;
  u16* m2t = (u16*)(ksum + 1024);
  u64* pf = (u64*)(m2t + 65536);
  u64* mf = pf + 1024;

  mega_kernel<<<1024, 256, 0, stream>>>(q, k, v, w, b, kT, vT, kvp, ksp, kmv,
                                        m2t, ksum, pf, mf, out);
}

// Round 5
// 246.502 us; speedup vs baseline: 3.7191x; 3.7191x over previous
//
#include <hip/hip_runtime.h>

// SparseLinearAttention: B=1, L=4096, H=16, D=64, BLKQ=BLKK=64, M=N=64, T=8.
// fp32 I/O. 2 dispatches:
//   prep(K one-pass: kT,kfmT,kvsum-partials,ksum-partials,km; V->vT)
// -> fusedpost: blocks m<4 per head reduce kvp+apply W -> m2 (m==4: ksum),
//    release per-head flags; ALL blocks run topk + K-loop, then RELAXED-poll
//    the 5 flags (checked ~25us after producers start) + one acquire fence,
//    then the linear part. No acquire-polling (R3 lesson), no prep flags.
// Single-use streams (k,v,kvp,ksp,out) use nontemporal ld/st so kT/vT stay
// L2-resident for the gather loop.

#define NH   16
#define DH   64
#define NBLK 64
#define TSEL 8

typedef unsigned short u16;
typedef unsigned int   u32;
typedef unsigned long long u64;
typedef __attribute__((ext_vector_type(8))) short short8;  // 8 bf16
typedef __attribute__((ext_vector_type(4))) float f4;
typedef __attribute__((ext_vector_type(4))) u32 u32x4;

#define MFMA_BF16(a, b, c) __builtin_amdgcn_mfma_f32_16x16x32_bf16(a, b, c, 0, 0, 0)
#define MAGIC64 0x2468ACE013579BDFull
#define SPIN_CAP 131072

__device__ __forceinline__ u16 f2bf_rne(float f) {
  u32 u = __float_as_uint(f);
  u += 0x7fffu + ((u >> 16) & 1u);
  return (u16)(u >> 16);
}
__device__ __forceinline__ u32 pk2(float a, float b) {
  return (u32)f2bf_rne(a) | ((u32)f2bf_rne(b) << 16);
}
__device__ __forceinline__ float bf2f(u16 u) { return __uint_as_float(((u32)u) << 16); }

// 8-bf16 fragment from a swizzled row-major bf16 tile (128B rows; logical
// 16B block j of row r stored at j^(r&7)).
__device__ __forceinline__ short8 frag_row(const u16* t, int row, int jblk) {
  return *(const short8*)((const char*)t + row * 128 + ((jblk ^ (row & 7)) * 16));
}

// ---------------- K_A: one-pass prep over K/V ------------------------------
// grid 1024 (XCD-swizzled: h = 2*(b&7) + (b>>9), n = (b>>3)&63), 256 thr.
__global__ __launch_bounds__(256) void prep_kernel(const float* __restrict__ k,
                                                   const float* __restrict__ v,
                                                   u16* __restrict__ kT,
                                                   u16* __restrict__ vT,
                                                   float* __restrict__ kvp,
                                                   float* __restrict__ ksp,
                                                   float* __restrict__ kmv) {
  __shared__ __align__(16) char vsl[8192];    // V^T bf16 swizzled
  __shared__ __align__(16) char kfm[8192];    // kfm^T bf16 swizzled
  __shared__ float kcol[64 * 65];             // raw K, column-major (km)
  __shared__ float redmx[256];
  __shared__ float redsm[256];
  __shared__ float kmred[256];
  __shared__ float ksred[256];
  int b = blockIdx.x;
  int n = (b >> 3) & 63;
  int h = 2 * (b & 7) + (b >> 9);
  int tid = threadIdx.x;
  int w = tid >> 6, lane = tid & 63;
  int row = lane, qd = w;
  int lq = lane & 15, quad = lane >> 4;

  // ---- K row segment (16 floats), nontemporal (single-use stream) ----
  float kv[16];
  {
    const f4* kr = (const f4*)(k + (size_t)(n * 64 + row) * 1024 + h * 64 + qd * 16);
#pragma unroll
    for (int c4 = 0; c4 < 4; c4++) {
      f4 a = __builtin_nontemporal_load(kr + c4);
      kv[c4 * 4] = a[0]; kv[c4 * 4 + 1] = a[1]; kv[c4 * 4 + 2] = a[2]; kv[c4 * 4 + 3] = a[3];
    }
  }
  // ---- kT global write (raw bf16, swizzled row layout; keep cached) ----
  {
    char* ktb = (char*)(kT + ((size_t)(h * 64 + n)) * 4096);
    uint4 w0 = make_uint4(pk2(kv[0], kv[1]), pk2(kv[2], kv[3]),
                          pk2(kv[4], kv[5]), pk2(kv[6], kv[7]));
    uint4 w1 = make_uint4(pk2(kv[8], kv[9]), pk2(kv[10], kv[11]),
                          pk2(kv[12], kv[13]), pk2(kv[14], kv[15]));
    *(uint4*)(ktb + row * 128 + (((2 * qd) ^ (row & 7)) * 16)) = w0;
    *(uint4*)(ktb + row * 128 + (((2 * qd + 1) ^ (row & 7)) * 16)) = w1;
  }
  // ---- raw K into column-major LDS (for km) ----
  {
#pragma unroll
    for (int j = 0; j < 16; j++) kcol[(qd * 16 + j) * 65 + row] = kv[j];
  }
  // ---- V^T into LDS (scalar transpose scatter) ----
  {
    const f4* vr = (const f4*)(v + (size_t)(n * 64 + row) * 1024 + h * 64 + qd * 16);
    int kb = row >> 3, klo = row & 7;
#pragma unroll
    for (int c4 = 0; c4 < 4; c4++) {
      f4 a = __builtin_nontemporal_load(vr + c4);
      float vv[4] = {a[0], a[1], a[2], a[3]};
#pragma unroll
      for (int jj = 0; jj < 4; jj++) {
        int e = qd * 16 + c4 * 4 + jj;
        *(u16*)(vsl + e * 128 + ((kb ^ (e & 7)) * 16) + klo * 2) = f2bf_rne(vv[jj]);
      }
    }
  }
  // ---- row max partial ----
  {
    float mx = kv[0];
#pragma unroll
    for (int j = 1; j < 16; j++) mx = fmaxf(mx, kv[j]);
    redmx[qd * 64 + row] = mx;
  }
  __syncthreads();
  // ---- km partials ----
  {
    int c = tid & 63, g = tid >> 6;
    float pk = 0.f;
#pragma unroll
    for (int i = 0; i < 16; i++) pk += kcol[c * 65 + g * 16 + i];
    kmred[g * 64 + c] = pk;
  }
  // ---- row softmax: max fold + exp + sum partial ----
  {
    float mx = fmaxf(fmaxf(redmx[row], redmx[64 + row]),
                     fmaxf(redmx[128 + row], redmx[192 + row]));
    float sm = 0.f;
#pragma unroll
    for (int j = 0; j < 16; j++) { kv[j] = __expf(kv[j] - mx); sm += kv[j]; }
    redsm[qd * 64 + row] = sm;
  }
  __syncthreads();
  if (tid < 64)
    kmv[h * 4096 + n * 64 + tid] =
        (kmred[tid] + kmred[64 + tid] + kmred[128 + tid] + kmred[192 + tid]) * (1.0f / 64.0f);
  {
    float sm = redsm[row] + redsm[64 + row] + redsm[128 + row] + redsm[192 + row];
    float inv = 1.0f / sm;
    int rb = row >> 3, rlo = row & 7;
#pragma unroll
    for (int j = 0; j < 16; j++) {
      int d = qd * 16 + j;
      *(u16*)(kfm + d * 128 + (((rb) ^ (d & 7)) * 16) + rlo * 2) = f2bf_rne(kv[j] * inv);
    }
  }
  __syncthreads();   // kfm + vsl complete

  // ---- vT global copy (keep cached) ----
  {
    uint4* vt_out = (uint4*)(vT + ((size_t)(h * 64 + n)) * 4096);
    vt_out[tid] = ((const uint4*)vsl)[tid];
    vt_out[256 + tid] = ((const uint4*)vsl)[256 + tid];
  }
  // ---- ksum partial ----
  {
    float ks = 0.f;
    short8 x0 = frag_row((const u16*)kfm, lane, 2 * w);
    short8 x1 = frag_row((const u16*)kfm, lane, 2 * w + 1);
#pragma unroll
    for (int e = 0; e < 8; e++) ks += bf2f((u16)x0[e]) + bf2f((u16)x1[e]);
    ksred[tid] = ks;
  }
  // ---- kvsum MFMA partial -> nontemporal global store ----
  {
    f4 acc[4];
    f4 zz = {0.f, 0.f, 0.f, 0.f};
#pragma unroll
    for (int et = 0; et < 4; et++) acc[et] = zz;
#pragma unroll
    for (int ks2 = 0; ks2 < 2; ks2++) {
      short8 a_ = frag_row((const u16*)kfm, w * 16 + lq, 4 * ks2 + quad);
#pragma unroll
      for (int et = 0; et < 4; et++)
        acc[et] = MFMA_BF16(a_, frag_row((const u16*)vsl, et * 16 + lq, 4 * ks2 + quad), acc[et]);
    }
    float* kvb = kvp + ((size_t)(h * 64 + n)) * 4096;
#pragma unroll
    for (int r = 0; r < 4; r++)
#pragma unroll
      for (int et = 0; et < 4; et++)
        __builtin_nontemporal_store(acc[et][r],
            kvb + (w * 16 + quad * 4 + r) * 64 + et * 16 + lq);
  }
  __syncthreads();
  if (tid < 64)
    __builtin_nontemporal_store(ksred[tid] + ksred[64 + tid] +
                                ksred[128 + tid] + ksred[192 + tid],
                                ksp + ((size_t)(h * 64 + n)) * 64 + tid);
}

// ---------------- K_B: fusedpost ------------------------------------------
// grid 1024 1D, XCD-swizzled (each XCD owns 2 heads). 256 thr = 4 waves.
// m<4: m2 slice producer (bit-identical to old post); m==4: ksum reducer.
// Then all blocks: topk -> K-loop -> relaxed-poll mf -> linear part.
// LDS 24576 -> 6 blk/CU capacity (1536 >= 1024: all co-resident).
__global__ __launch_bounds__(256, 4) void fusedpost_kernel(const float* __restrict__ q,
                                                           const u16* __restrict__ kT,
                                                           const u16* __restrict__ vT,
                                                           const float* __restrict__ kvp,
                                                           const float* __restrict__ ksp,
                                                           const float* __restrict__ kmv,
                                                           const float* __restrict__ wgt,
                                                           const float* __restrict__ bproj,
                                                           u16* __restrict__ m2t,
                                                           float* __restrict__ ksum,
                                                           u64* __restrict__ mf,
                                                           float* __restrict__ out) {
  __shared__ __align__(16) char smem[24576];
  // producer era: wl[64*65]f32 @0 (16632B) | red16[16*64]f32 @18048
  // topk era:     km_s @0 (16640) | qmp @16640 | qmf @17664
  // K-loop era:   buf @0 (16K: K 8K + V^T 8K) | P @16384 (2K/wave)
  // linear era:   m2 @0 | ksum @8192 | bias @8448
  int b = blockIdx.x;
  int m = (b >> 3) & 63;
  int h = 2 * (b & 7) + (b >> 9);
  int tid = threadIdx.x, w = tid >> 6, lane = tid & 63;
  int lq = lane & 15, quad = lane >> 4;
  char* buf = smem;
  char* p_b = smem + 16384 + w * 2048;

  // ======= PHASE A: producers (m<5) =======
  if (m < 4) {
    float* wl = (float*)smem;
    float* red16 = (float*)(smem + 18048);
    int j = tid & 63, rr = tid >> 6;
#pragma unroll
    for (int i = 0; i < 16; i++) {
      int f = i * 256 + tid;
      wl[(f >> 6) * 65 + (f & 63)] = wgt[f];
    }
#pragma unroll
    for (int s = 0; s < 4; s++) {
      int d = m * 16 + s * 4 + rr;
      const float* base = kvp + (size_t)h * 64 * 4096 + d * 64 + j;
      float s0 = 0.f, s1 = 0.f, s2 = 0.f, s3 = 0.f;
#pragma unroll
      for (int n4 = 0; n4 < 16; n4++) {
        s0 += __builtin_nontemporal_load(base + (size_t)(n4 * 4 + 0) * 4096);
        s1 += __builtin_nontemporal_load(base + (size_t)(n4 * 4 + 1) * 4096);
        s2 += __builtin_nontemporal_load(base + (size_t)(n4 * 4 + 2) * 4096);
        s3 += __builtin_nontemporal_load(base + (size_t)(n4 * 4 + 3) * 4096);
      }
      red16[(s * 4 + rr) * 64 + j] = (s0 + s1) + (s2 + s3);
    }
    __syncthreads();
    int e = tid & 63, rr2 = tid >> 6;
#pragma unroll
    for (int s = 0; s < 4; s++) {
      int dloc = s * 4 + rr2;
      float acc = 0.f;
#pragma unroll
      for (int jj = 0; jj < 64; jj++)
        acc = fmaf(red16[dloc * 64 + jj], wl[e * 65 + jj], acc);
      int d = m * 16 + dloc;
      *(u16*)((char*)m2t + (size_t)h * 8192 + e * 128 +
              (((d >> 3) ^ (e & 7)) * 16) + (d & 7) * 2) = f2bf_rne(acc);
    }
  } else if (m == 4) {
    if (tid < 64) {
      const float* base = ksp + (size_t)h * 64 * 64 + tid;
      float s = 0.f;
#pragma unroll
      for (int n = 0; n < 64; n++) s += __builtin_nontemporal_load(base + (size_t)n * 64);
      ksum[h * 64 + tid] = s;
    }
  }
  if (m < 5) {
    __threadfence();
    __syncthreads();
    if (tid == 0)
      __hip_atomic_store(mf + h * 5 + m, MAGIC64, __ATOMIC_RELEASE,
                         __HIP_MEMORY_SCOPE_AGENT);
    __syncthreads();   // LDS free for topk era
  }

  // ======= PHASE B: topk (q-block mean vs km, butterfly top-8) =======
  float* km_s = (float*)smem;
  float* qmp = (float*)(smem + 16640);
  float* qmf = (float*)(smem + 17664);
  {
    int c = tid & 63, g = tid >> 6;
    const float* qcol = q + ((size_t)(m * 64 + g * 16)) * 1024 + h * 64 + c;
    float qp = 0.f;
#pragma unroll
    for (int i = 0; i < 16; i++) qp += qcol[(size_t)i * 1024];
    qmp[g * 64 + c] = qp;
#pragma unroll
    for (int i = 0; i < 16; i++) {
      int idx = i * 256 + tid;
      km_s[(idx >> 6) * 65 + (idx & 63)] = kmv[h * 4096 + idx];
    }
  }
  __syncthreads();
  if (tid < 64) qmf[tid] = qmp[tid] + qmp[64 + tid] + qmp[128 + tid] + qmp[192 + tid];
  __syncthreads();
  int blks[8];
  {
    int n = lane;
    float s = 0.f;
#pragma unroll
    for (int d = 0; d < 64; d++) s += qmf[d] * km_s[n * 65 + d];
    float my = s;
#pragma unroll
    for (int t = 0; t < TSEL; t++) {
      float vv = my; int idx = n;
#pragma unroll
      for (int off = 1; off < 64; off <<= 1) {
        float ov = __shfl_xor(vv, off);
        int oi = __shfl_xor(idx, off);
        if (ov > vv || (ov == vv && oi < idx)) { vv = ov; idx = oi; }
      }
      int sel = __builtin_amdgcn_readfirstlane(idx);
      blks[t] = sel;
      if (n == sel) my = -INFINITY;
    }
  }
  __syncthreads();   // km_s dead

  // ======= PHASE C: block-sparse attention K-loop =======
  const int qrow = w * 16 + lq;
  const float* qr_g = q + ((size_t)(m * 64 + qrow)) * 1024 + h * 64;
  short8 qf[2];
#pragma unroll
  for (int ks = 0; ks < 2; ks++) {
    const float* gp = qr_g + (4 * ks + quad) * 8;
    float4 a = *(const float4*)gp;
    float4 bb = *(const float4*)(gp + 4);
    u32x4 tt = {pk2(a.x, a.y), pk2(a.z, a.w), pk2(bb.x, bb.y), pk2(bb.z, bb.w)};
    qf[ks] = __builtin_bit_cast(short8, tt);
  }

  { // stage K/V block 0
    const uint4* kt0 = (const uint4*)(kT + ((size_t)(h * 64 + blks[0])) * 4096);
    const uint4* vt0 = (const uint4*)(vT + ((size_t)(h * 64 + blks[0])) * 4096);
    ((uint4*)buf)[tid] = kt0[tid];
    ((uint4*)buf)[256 + tid] = kt0[256 + tid];
    ((uint4*)(buf + 8192))[tid] = vt0[tid];
    ((uint4*)(buf + 8192))[256 + tid] = vt0[256 + tid];
  }
  __syncthreads();

  float mrun = -INFINITY, lrun = 0.f;
  f4 o[4];
  f4 zz = {0.f, 0.f, 0.f, 0.f};
#pragma unroll
  for (int et = 0; et < 4; et++) o[et] = zz;

  const u16* kc = (const u16*)buf;
  const u16* vc = (const u16*)(buf + 8192);

  for (int t = 0; t < 8; t++) {
    uint4 pk0, pk1, pv0, pv1;
    if (t < 7) {
      const uint4* ktn = (const uint4*)(kT + ((size_t)(h * 64 + blks[t + 1])) * 4096);
      const uint4* vtn = (const uint4*)(vT + ((size_t)(h * 64 + blks[t + 1])) * 4096);
      pk0 = ktn[tid]; pk1 = ktn[256 + tid];
      pv0 = vtn[tid]; pv1 = vtn[256 + tid];
    }

    // S^T = K·Q^T
    f4 s[4];
#pragma unroll
    for (int kt = 0; kt < 4; kt++) s[kt] = zz;
    __builtin_amdgcn_s_setprio(1);
#pragma unroll
    for (int ks = 0; ks < 2; ks++)
#pragma unroll
      for (int kt = 0; kt < 4; kt++)
        s[kt] = MFMA_BF16(frag_row(kc, kt * 16 + lq, 4 * ks + quad), qf[ks], s[kt]);
    __builtin_amdgcn_s_setprio(0);

    // online softmax (16 scores/lane)
    float mp = -INFINITY;
#pragma unroll
    for (int kt = 0; kt < 4; kt++)
#pragma unroll
      for (int r = 0; r < 4; r++) mp = fmaxf(mp, s[kt][r]);
    mp = fmaxf(mp, __shfl_xor(mp, 16));
    mp = fmaxf(mp, __shfl_xor(mp, 32));
    mp *= 0.125f;
    if (__any(mp > mrun)) {
      float mn = fmaxf(mrun, mp);
      float al = __expf(mrun - mn);
      mrun = mn;
      lrun *= al;
#pragma unroll
      for (int et = 0; et < 4; et++)
#pragma unroll
        for (int r = 0; r < 4; r++) o[et][r] *= al;
    }
    float rs_ = 0.f;
#pragma unroll
    for (int kt = 0; kt < 4; kt++) {
      float p0 = __expf(fmaf(s[kt][0], 0.125f, -mrun));
      float p1 = __expf(fmaf(s[kt][1], 0.125f, -mrun));
      float p2 = __expf(fmaf(s[kt][2], 0.125f, -mrun));
      float p3 = __expf(fmaf(s[kt][3], 0.125f, -mrun));
      rs_ += p0 + p1 + p2 + p3;
      u32 lo32 = (__float_as_uint(p0) >> 16) | (__float_as_uint(p1) & 0xffff0000u);
      u32 hi32 = (__float_as_uint(p2) >> 16) | (__float_as_uint(p3) & 0xffff0000u);
      int addr = lq * 128 + (((kt * 2 + (quad >> 1)) ^ (lq & 7)) * 16) + (quad & 1) * 8;
      *(uint2*)(p_b + addr) = make_uint2(lo32, hi32);
    }
    rs_ += __shfl_xor(rs_, 16);
    rs_ += __shfl_xor(rs_, 32);
    lrun += rs_;

    // O^T += V^T · P^T
    __builtin_amdgcn_s_setprio(1);
#pragma unroll
    for (int ks = 0; ks < 2; ks++) {
      short8 pfr = frag_row((const u16*)p_b, lq, 4 * ks + quad);
#pragma unroll
      for (int et = 0; et < 4; et++)
        o[et] = MFMA_BF16(frag_row(vc, et * 16 + lq, 4 * ks + quad), pfr, o[et]);
    }
    __builtin_amdgcn_s_setprio(0);

    if (t < 7) {
      __syncthreads();
      ((uint4*)buf)[tid] = pk0;
      ((uint4*)buf)[256 + tid] = pk1;
      ((uint4*)(buf + 8192))[tid] = pv0;
      ((uint4*)(buf + 8192))[256 + tid] = pv1;
      __syncthreads();
    }
  }

  // ======= PHASE D: RELAXED-poll mf flags + single acquire fence =======
  __syncthreads();
  if (tid < 5) {
    const u64* fp1 = mf + h * 5 + tid;
    int c = 0;
    while (__hip_atomic_load(fp1, __ATOMIC_RELAXED, __HIP_MEMORY_SCOPE_AGENT) != MAGIC64) {
      if (++c > SPIN_CAP) break;
      __builtin_amdgcn_s_sleep(8);
    }
  }
  __syncthreads();
  __builtin_amdgcn_fence(__ATOMIC_ACQUIRE, "agent");
  {
    const uint4* src = (const uint4*)((const char*)m2t + (size_t)h * 8192);
    ((uint4*)buf)[tid] = src[tid];
    ((uint4*)buf)[256 + tid] = src[256 + tid];
    if (tid < 64) {
      ((float*)(buf + 8192))[tid] = ksum[h * 64 + tid];
      ((float*)(buf + 8448))[tid] = bproj[tid];
    }
  }
  __syncthreads();
  u16* m2_l = (u16*)buf;
  float* ks_s = (float*)(buf + 8192);
  float* b_s = (float*)(buf + 8448);

  float ev[16];
  float mx = -INFINITY;
#pragma unroll
  for (int c4 = 0; c4 < 4; c4++) {
    float4 a = *(const float4*)(qr_g + quad * 16 + c4 * 4);
    ev[c4 * 4] = a.x; ev[c4 * 4 + 1] = a.y; ev[c4 * 4 + 2] = a.z; ev[c4 * 4 + 3] = a.w;
    mx = fmaxf(mx, fmaxf(fmaxf(a.x, a.y), fmaxf(a.z, a.w)));
  }
  mx = fmaxf(mx, __shfl_xor(mx, 16));
  mx = fmaxf(mx, __shfl_xor(mx, 32));
  float sum = 0.f, eks = 0.f;
#pragma unroll
  for (int j = 0; j < 16; j++) {
    float e = __expf(ev[j] - mx);
    ev[j] = e;
    sum += e;
    eks += e * ks_s[quad * 16 + j];
  }
  sum += __shfl_xor(sum, 16); sum += __shfl_xor(sum, 32);
  eks += __shfl_xor(eks, 16); eks += __shfl_xor(eks, 32);
  float invs = 1.0f / sum;
  float den = fmaf(eks, invs, 1e-6f);
  float scale = invs / den;
  uint4 e0v = make_uint4(pk2(ev[0], ev[1]), pk2(ev[2], ev[3]),
                         pk2(ev[4], ev[5]), pk2(ev[6], ev[7]));
  uint4 e1v = make_uint4(pk2(ev[8], ev[9]), pk2(ev[10], ev[11]),
                         pk2(ev[12], ev[13]), pk2(ev[14], ev[15]));
  *(uint4*)(p_b + lq * 128 + (((2 * quad) ^ (lq & 7)) * 16)) = e0v;
  *(uint4*)(p_b + lq * 128 + (((2 * quad + 1) ^ (lq & 7)) * 16)) = e1v;

  f4 oc[4];
  f4 zz2 = {0.f, 0.f, 0.f, 0.f};
#pragma unroll
  for (int et = 0; et < 4; et++) oc[et] = zz2;
  __builtin_amdgcn_s_setprio(1);
#pragma unroll
  for (int ks2 = 0; ks2 < 2; ks2++) {
    short8 ef = frag_row((const u16*)p_b, lq, 4 * ks2 + quad);
#pragma unroll
    for (int et = 0; et < 4; et++)
      oc[et] = MFMA_BF16(frag_row(m2_l, et * 16 + lq, 4 * ks2 + quad), ef, oc[et]);
  }
  __builtin_amdgcn_s_setprio(0);

  // ---- single write: out = o_s/l + o_l*scale + bias (nontemporal) ----
  float invl = 1.0f / lrun;
  float* gp = out + ((size_t)(m * 64 + qrow)) * 1024 + h * 64 + quad * 4;
#pragma unroll
  for (int et = 0; et < 4; et++) {
    int e0 = et * 16 + quad * 4;
    f4 ov;
    ov[0] = o[et][0] * invl + oc[et][0] * scale + b_s[e0 + 0];
    ov[1] = o[et][1] * invl + oc[et][1] * scale + b_s[e0 + 1];
    ov[2] = o[et][2] * invl + oc[et][2] * scale + b_s[e0 + 2];
    ov[3] = o[et][3] * invl + oc[et][3] * scale + b_s[e0 + 3];
    __builtin_nontemporal_store(ov, (f4*)(gp + et * 16));
  }
}

extern "C" void kernel_launch(void* const* d_in, const int* in_sizes, int n_in,
                              void* d_out, int out_size, void* d_ws, size_t ws_size,
                              hipStream_t stream) {
  const float* q = (const float*)d_in[0];
  const float* k = (const float*)d_in[1];
  const float* v = (const float*)d_in[2];
  const float* w = (const float*)d_in[3];
  const float* b = (const float*)d_in[4];
  float* out = (float*)d_out;

  // ws: kT 8MB u16 | vT 8MB u16 | kvp 16MB f32 | ksp 256KB f32 |
  //     kmv 256KB f32 | ksum 4KB f32 | m2t 128KB u16 | mf 640B u64
  u16* kT = (u16*)d_ws;
  u16* vT = kT + 4194304;
  float* kvp = (float*)(vT + 4194304);
  float* ksp = kvp + 4194304;
  float* kmv = ksp + 65536;
  float* ksum = kmv + 65536;
  u16* m2t = (u16*)(ksum + 1024);
  u64* mf = (u64*)(m2t + 65536);

  prep_kernel<<<1024, 256, 0, stream>>>(k, v, kT, vT, kvp, ksp, kmv);
  fusedpost_kernel<<<1024, 256, 0, stream>>>(q, kT, vT, kvp, ksp, kmv, w, b,
                                             m2t, ksum, mf, out);
}

// Round 6
// 210.730 us; speedup vs baseline: 4.3504x; 1.1698x over previous
//
#include <hip/hip_runtime.h>

// SparseLinearAttention: B=1, L=4096, H=16, D=64, BLKQ=BLKK=64, M=N=64, T=8.
// fp32 I/O. 2 dispatches:
//   prep(K one-pass: kT,kfmT,kvsum-partials,ksum-partials,km; V->vT)
// -> fusedpost: blocks m<4 per head reduce kvp+apply W -> m2 (m==4: ksum),
//    release per-head flags; ALL blocks run topk + K-loop, then RELAXED-poll
//    the 5 flags + one acquire fence, then the linear part.
// NO nontemporal accesses anywhere (R5 lesson: NT scalar/scattered stores
// bypass L2 write-combining -> DRAM burst amplification, 2.5-3x slowdown).

#define NH   16
#define DH   64
#define NBLK 64
#define TSEL 8

typedef unsigned short u16;
typedef unsigned int   u32;
typedef unsigned long long u64;
typedef __attribute__((ext_vector_type(8))) short short8;  // 8 bf16
typedef __attribute__((ext_vector_type(4))) float f4;
typedef __attribute__((ext_vector_type(4))) u32 u32x4;

#define MFMA_BF16(a, b, c) __builtin_amdgcn_mfma_f32_16x16x32_bf16(a, b, c, 0, 0, 0)
#define MAGIC64 0x2468ACE013579BDFull
#define SPIN_CAP 131072

__device__ __forceinline__ u16 f2bf_rne(float f) {
  u32 u = __float_as_uint(f);
  u += 0x7fffu + ((u >> 16) & 1u);
  return (u16)(u >> 16);
}
__device__ __forceinline__ u32 pk2(float a, float b) {
  return (u32)f2bf_rne(a) | ((u32)f2bf_rne(b) << 16);
}
__device__ __forceinline__ float bf2f(u16 u) { return __uint_as_float(((u32)u) << 16); }

// 8-bf16 fragment from a swizzled row-major bf16 tile (128B rows; logical
// 16B block j of row r stored at j^(r&7)).
__device__ __forceinline__ short8 frag_row(const u16* t, int row, int jblk) {
  return *(const short8*)((const char*)t + row * 128 + ((jblk ^ (row & 7)) * 16));
}

// ---------------- K_A: one-pass prep over K/V ------------------------------
// grid 1024 (XCD-swizzled: h = 2*(b&7) + (b>>9), n = (b>>3)&63), 256 thr.
__global__ __launch_bounds__(256) void prep_kernel(const float* __restrict__ k,
                                                   const float* __restrict__ v,
                                                   u16* __restrict__ kT,
                                                   u16* __restrict__ vT,
                                                   float* __restrict__ kvp,
                                                   float* __restrict__ ksp,
                                                   float* __restrict__ kmv) {
  __shared__ __align__(16) char vsl[8192];    // V^T bf16 swizzled
  __shared__ __align__(16) char kfm[8192];    // kfm^T bf16 swizzled
  __shared__ float kcol[64 * 65];             // raw K, column-major (km)
  __shared__ float redmx[256];
  __shared__ float redsm[256];
  __shared__ float kmred[256];
  __shared__ float ksred[256];
  int b = blockIdx.x;
  int n = (b >> 3) & 63;
  int h = 2 * (b & 7) + (b >> 9);
  int tid = threadIdx.x;
  int w = tid >> 6, lane = tid & 63;
  int row = lane, qd = w;
  int lq = lane & 15, quad = lane >> 4;

  // ---- K row segment (16 floats) ----
  float kv[16];
  {
    const float* kr = k + (size_t)(n * 64 + row) * 1024 + h * 64 + qd * 16;
#pragma unroll
    for (int c4 = 0; c4 < 4; c4++) {
      float4 a = *(const float4*)(kr + c4 * 4);
      kv[c4 * 4] = a.x; kv[c4 * 4 + 1] = a.y; kv[c4 * 4 + 2] = a.z; kv[c4 * 4 + 3] = a.w;
    }
  }
  // ---- kT global write (raw bf16, swizzled row layout) ----
  {
    char* ktb = (char*)(kT + ((size_t)(h * 64 + n)) * 4096);
    uint4 w0 = make_uint4(pk2(kv[0], kv[1]), pk2(kv[2], kv[3]),
                          pk2(kv[4], kv[5]), pk2(kv[6], kv[7]));
    uint4 w1 = make_uint4(pk2(kv[8], kv[9]), pk2(kv[10], kv[11]),
                          pk2(kv[12], kv[13]), pk2(kv[14], kv[15]));
    *(uint4*)(ktb + row * 128 + (((2 * qd) ^ (row & 7)) * 16)) = w0;
    *(uint4*)(ktb + row * 128 + (((2 * qd + 1) ^ (row & 7)) * 16)) = w1;
  }
  // ---- raw K into column-major LDS (for km) ----
  {
#pragma unroll
    for (int j = 0; j < 16; j++) kcol[(qd * 16 + j) * 65 + row] = kv[j];
  }
  // ---- V^T into LDS (scalar transpose scatter) ----
  {
    const float* vr = v + (size_t)(n * 64 + row) * 1024 + h * 64 + qd * 16;
    int kb = row >> 3, klo = row & 7;
#pragma unroll
    for (int c4 = 0; c4 < 4; c4++) {
      float4 a = *(const float4*)(vr + c4 * 4);
      float vv[4] = {a.x, a.y, a.z, a.w};
#pragma unroll
      for (int jj = 0; jj < 4; jj++) {
        int e = qd * 16 + c4 * 4 + jj;
        *(u16*)(vsl + e * 128 + ((kb ^ (e & 7)) * 16) + klo * 2) = f2bf_rne(vv[jj]);
      }
    }
  }
  // ---- row max partial ----
  {
    float mx = kv[0];
#pragma unroll
    for (int j = 1; j < 16; j++) mx = fmaxf(mx, kv[j]);
    redmx[qd * 64 + row] = mx;
  }
  __syncthreads();
  // ---- km partials ----
  {
    int c = tid & 63, g = tid >> 6;
    float pk = 0.f;
#pragma unroll
    for (int i = 0; i < 16; i++) pk += kcol[c * 65 + g * 16 + i];
    kmred[g * 64 + c] = pk;
  }
  // ---- row softmax: max fold + exp + sum partial ----
  {
    float mx = fmaxf(fmaxf(redmx[row], redmx[64 + row]),
                     fmaxf(redmx[128 + row], redmx[192 + row]));
    float sm = 0.f;
#pragma unroll
    for (int j = 0; j < 16; j++) { kv[j] = __expf(kv[j] - mx); sm += kv[j]; }
    redsm[qd * 64 + row] = sm;
  }
  __syncthreads();
  if (tid < 64)
    kmv[h * 4096 + n * 64 + tid] =
        (kmred[tid] + kmred[64 + tid] + kmred[128 + tid] + kmred[192 + tid]) * (1.0f / 64.0f);
  {
    float sm = redsm[row] + redsm[64 + row] + redsm[128 + row] + redsm[192 + row];
    float inv = 1.0f / sm;
    int rb = row >> 3, rlo = row & 7;
#pragma unroll
    for (int j = 0; j < 16; j++) {
      int d = qd * 16 + j;
      *(u16*)(kfm + d * 128 + (((rb) ^ (d & 7)) * 16) + rlo * 2) = f2bf_rne(kv[j] * inv);
    }
  }
  __syncthreads();   // kfm + vsl complete

  // ---- vT global copy ----
  {
    uint4* vt_out = (uint4*)(vT + ((size_t)(h * 64 + n)) * 4096);
    vt_out[tid] = ((const uint4*)vsl)[tid];
    vt_out[256 + tid] = ((const uint4*)vsl)[256 + tid];
  }
  // ---- ksum partial ----
  {
    float ks = 0.f;
    short8 x0 = frag_row((const u16*)kfm, lane, 2 * w);
    short8 x1 = frag_row((const u16*)kfm, lane, 2 * w + 1);
#pragma unroll
    for (int e = 0; e < 8; e++) ks += bf2f((u16)x0[e]) + bf2f((u16)x1[e]);
    ksred[tid] = ks;
  }
  // ---- kvsum MFMA partial -> plain global store ----
  {
    f4 acc[4];
    f4 zz = {0.f, 0.f, 0.f, 0.f};
#pragma unroll
    for (int et = 0; et < 4; et++) acc[et] = zz;
#pragma unroll
    for (int ks2 = 0; ks2 < 2; ks2++) {
      short8 a_ = frag_row((const u16*)kfm, w * 16 + lq, 4 * ks2 + quad);
#pragma unroll
      for (int et = 0; et < 4; et++)
        acc[et] = MFMA_BF16(a_, frag_row((const u16*)vsl, et * 16 + lq, 4 * ks2 + quad), acc[et]);
    }
    float* kvb = kvp + ((size_t)(h * 64 + n)) * 4096;
#pragma unroll
    for (int r = 0; r < 4; r++)
#pragma unroll
      for (int et = 0; et < 4; et++)
        kvb[(w * 16 + quad * 4 + r) * 64 + et * 16 + lq] = acc[et][r];
  }
  __syncthreads();
  if (tid < 64)
    ksp[((size_t)(h * 64 + n)) * 64 + tid] = ksred[tid] + ksred[64 + tid] +
                                             ksred[128 + tid] + ksred[192 + tid];
}

// ---------------- K_B: fusedpost ------------------------------------------
// grid 1024 1D, XCD-swizzled (each XCD owns 2 heads). 256 thr = 4 waves.
// m<4: m2 slice producer (bit-identical to old post); m==4: ksum reducer.
// Then all blocks: topk -> K-loop -> relaxed-poll mf -> linear part.
// LDS 24576 -> 6 blk/CU capacity (1536 >= 1024: all co-resident).
__global__ __launch_bounds__(256, 4) void fusedpost_kernel(const float* __restrict__ q,
                                                           const u16* __restrict__ kT,
                                                           const u16* __restrict__ vT,
                                                           const float* __restrict__ kvp,
                                                           const float* __restrict__ ksp,
                                                           const float* __restrict__ kmv,
                                                           const float* __restrict__ wgt,
                                                           const float* __restrict__ bproj,
                                                           u16* __restrict__ m2t,
                                                           float* __restrict__ ksum,
                                                           u64* __restrict__ mf,
                                                           float* __restrict__ out) {
  __shared__ __align__(16) char smem[24576];
  // producer era: wl[64*65]f32 @0 (16632B) | red16[16*64]f32 @18048
  // topk era:     km_s @0 (16640) | qmp @16640 | qmf @17664
  // K-loop era:   buf @0 (16K: K 8K + V^T 8K) | P @16384 (2K/wave)
  // linear era:   m2 @0 | ksum @8192 | bias @8448
  int b = blockIdx.x;
  int m = (b >> 3) & 63;
  int h = 2 * (b & 7) + (b >> 9);
  int tid = threadIdx.x, w = tid >> 6, lane = tid & 63;
  int lq = lane & 15, quad = lane >> 4;
  char* buf = smem;
  char* p_b = smem + 16384 + w * 2048;

  // ======= PHASE A: producers (m<5) =======
  if (m < 4) {
    float* wl = (float*)smem;
    float* red16 = (float*)(smem + 18048);
    int j = tid & 63, rr = tid >> 6;
#pragma unroll
    for (int i = 0; i < 16; i++) {
      int f = i * 256 + tid;
      wl[(f >> 6) * 65 + (f & 63)] = wgt[f];
    }
#pragma unroll
    for (int s = 0; s < 4; s++) {
      int d = m * 16 + s * 4 + rr;
      const float* base = kvp + (size_t)h * 64 * 4096 + d * 64 + j;
      float s0 = 0.f, s1 = 0.f, s2 = 0.f, s3 = 0.f;
#pragma unroll
      for (int n4 = 0; n4 < 16; n4++) {
        s0 += base[(size_t)(n4 * 4 + 0) * 4096];
        s1 += base[(size_t)(n4 * 4 + 1) * 4096];
        s2 += base[(size_t)(n4 * 4 + 2) * 4096];
        s3 += base[(size_t)(n4 * 4 + 3) * 4096];
      }
      red16[(s * 4 + rr) * 64 + j] = (s0 + s1) + (s2 + s3);
    }
    __syncthreads();
    int e = tid & 63, rr2 = tid >> 6;
#pragma unroll
    for (int s = 0; s < 4; s++) {
      int dloc = s * 4 + rr2;
      float acc = 0.f;
#pragma unroll
      for (int jj = 0; jj < 64; jj++)
        acc = fmaf(red16[dloc * 64 + jj], wl[e * 65 + jj], acc);
      int d = m * 16 + dloc;
      *(u16*)((char*)m2t + (size_t)h * 8192 + e * 128 +
              (((d >> 3) ^ (e & 7)) * 16) + (d & 7) * 2) = f2bf_rne(acc);
    }
  } else if (m == 4) {
    if (tid < 64) {
      const float* base = ksp + (size_t)h * 64 * 64 + tid;
      float s = 0.f;
#pragma unroll
      for (int n = 0; n < 64; n++) s += base[(size_t)n * 64];
      ksum[h * 64 + tid] = s;
    }
  }
  if (m < 5) {
    __threadfence();
    __syncthreads();
    if (tid == 0)
      __hip_atomic_store(mf + h * 5 + m, MAGIC64, __ATOMIC_RELEASE,
                         __HIP_MEMORY_SCOPE_AGENT);
    __syncthreads();   // LDS free for topk era
  }

  // ======= PHASE B: topk (q-block mean vs km, butterfly top-8) =======
  float* km_s = (float*)smem;
  float* qmp = (float*)(smem + 16640);
  float* qmf = (float*)(smem + 17664);
  {
    int c = tid & 63, g = tid >> 6;
    const float* qcol = q + ((size_t)(m * 64 + g * 16)) * 1024 + h * 64 + c;
    float qp = 0.f;
#pragma unroll
    for (int i = 0; i < 16; i++) qp += qcol[(size_t)i * 1024];
    qmp[g * 64 + c] = qp;
#pragma unroll
    for (int i = 0; i < 16; i++) {
      int idx = i * 256 + tid;
      km_s[(idx >> 6) * 65 + (idx & 63)] = kmv[h * 4096 + idx];
    }
  }
  __syncthreads();
  if (tid < 64) qmf[tid] = qmp[tid] + qmp[64 + tid] + qmp[128 + tid] + qmp[192 + tid];
  __syncthreads();
  int blks[8];
  {
    int n = lane;
    float s = 0.f;
#pragma unroll
    for (int d = 0; d < 64; d++) s += qmf[d] * km_s[n * 65 + d];
    float my = s;
#pragma unroll
    for (int t = 0; t < TSEL; t++) {
      float vv = my; int idx = n;
#pragma unroll
      for (int off = 1; off < 64; off <<= 1) {
        float ov = __shfl_xor(vv, off);
        int oi = __shfl_xor(idx, off);
        if (ov > vv || (ov == vv && oi < idx)) { vv = ov; idx = oi; }
      }
      int sel = __builtin_amdgcn_readfirstlane(idx);
      blks[t] = sel;
      if (n == sel) my = -INFINITY;
    }
  }
  __syncthreads();   // km_s dead

  // ======= PHASE C: block-sparse attention K-loop =======
  const int qrow = w * 16 + lq;
  const float* qr_g = q + ((size_t)(m * 64 + qrow)) * 1024 + h * 64;
  short8 qf[2];
#pragma unroll
  for (int ks = 0; ks < 2; ks++) {
    const float* gp = qr_g + (4 * ks + quad) * 8;
    float4 a = *(const float4*)gp;
    float4 bb = *(const float4*)(gp + 4);
    u32x4 tt = {pk2(a.x, a.y), pk2(a.z, a.w), pk2(bb.x, bb.y), pk2(bb.z, bb.w)};
    qf[ks] = __builtin_bit_cast(short8, tt);
  }

  { // stage K/V block 0
    const uint4* kt0 = (const uint4*)(kT + ((size_t)(h * 64 + blks[0])) * 4096);
    const uint4* vt0 = (const uint4*)(vT + ((size_t)(h * 64 + blks[0])) * 4096);
    ((uint4*)buf)[tid] = kt0[tid];
    ((uint4*)buf)[256 + tid] = kt0[256 + tid];
    ((uint4*)(buf + 8192))[tid] = vt0[tid];
    ((uint4*)(buf + 8192))[256 + tid] = vt0[256 + tid];
  }
  __syncthreads();

  float mrun = -INFINITY, lrun = 0.f;
  f4 o[4];
  f4 zz = {0.f, 0.f, 0.f, 0.f};
#pragma unroll
  for (int et = 0; et < 4; et++) o[et] = zz;

  const u16* kc = (const u16*)buf;
  const u16* vc = (const u16*)(buf + 8192);

  for (int t = 0; t < 8; t++) {
    uint4 pk0, pk1, pv0, pv1;
    if (t < 7) {
      const uint4* ktn = (const uint4*)(kT + ((size_t)(h * 64 + blks[t + 1])) * 4096);
      const uint4* vtn = (const uint4*)(vT + ((size_t)(h * 64 + blks[t + 1])) * 4096);
      pk0 = ktn[tid]; pk1 = ktn[256 + tid];
      pv0 = vtn[tid]; pv1 = vtn[256 + tid];
    }

    // S^T = K·Q^T
    f4 s[4];
#pragma unroll
    for (int kt = 0; kt < 4; kt++) s[kt] = zz;
    __builtin_amdgcn_s_setprio(1);
#pragma unroll
    for (int ks = 0; ks < 2; ks++)
#pragma unroll
      for (int kt = 0; kt < 4; kt++)
        s[kt] = MFMA_BF16(frag_row(kc, kt * 16 + lq, 4 * ks + quad), qf[ks], s[kt]);
    __builtin_amdgcn_s_setprio(0);

    // online softmax (16 scores/lane)
    float mp = -INFINITY;
#pragma unroll
    for (int kt = 0; kt < 4; kt++)
#pragma unroll
      for (int r = 0; r < 4; r++) mp = fmaxf(mp, s[kt][r]);
    mp = fmaxf(mp, __shfl_xor(mp, 16));
    mp = fmaxf(mp, __shfl_xor(mp, 32));
    mp *= 0.125f;
    if (__any(mp > mrun)) {
      float mn = fmaxf(mrun, mp);
      float al = __expf(mrun - mn);
      mrun = mn;
      lrun *= al;
#pragma unroll
      for (int et = 0; et < 4; et++)
#pragma unroll
        for (int r = 0; r < 4; r++) o[et][r] *= al;
    }
    float rs_ = 0.f;
#pragma unroll
    for (int kt = 0; kt < 4; kt++) {
      float p0 = __expf(fmaf(s[kt][0], 0.125f, -mrun));
      float p1 = __expf(fmaf(s[kt][1], 0.125f, -mrun));
      float p2 = __expf(fmaf(s[kt][2], 0.125f, -mrun));
      float p3 = __expf(fmaf(s[kt][3], 0.125f, -mrun));
      rs_ += p0 + p1 + p2 + p3;
      u32 lo32 = (__float_as_uint(p0) >> 16) | (__float_as_uint(p1) & 0xffff0000u);
      u32 hi32 = (__float_as_uint(p2) >> 16) | (__float_as_uint(p3) & 0xffff0000u);
      int addr = lq * 128 + (((kt * 2 + (quad >> 1)) ^ (lq & 7)) * 16) + (quad & 1) * 8;
      *(uint2*)(p_b + addr) = make_uint2(lo32, hi32);
    }
    rs_ += __shfl_xor(rs_, 16);
    rs_ += __shfl_xor(rs_, 32);
    lrun += rs_;

    // O^T += V^T · P^T
    __builtin_amdgcn_s_setprio(1);
#pragma unroll
    for (int ks = 0; ks < 2; ks++) {
      short8 pfr = frag_row((const u16*)p_b, lq, 4 * ks + quad);
#pragma unroll
      for (int et = 0; et < 4; et++)
        o[et] = MFMA_BF16(frag_row(vc, et * 16 + lq, 4 * ks + quad), pfr, o[et]);
    }
    __builtin_amdgcn_s_setprio(0);

    if (t < 7) {
      __syncthreads();
      ((uint4*)buf)[tid] = pk0;
      ((uint4*)buf)[256 + tid] = pk1;
      ((uint4*)(buf + 8192))[tid] = pv0;
      ((uint4*)(buf + 8192))[256 + tid] = pv1;
      __syncthreads();
    }
  }

  // ======= PHASE D: RELAXED-poll mf flags + single acquire fence =======
  __syncthreads();
  if (tid < 5) {
    const u64* fp1 = mf + h * 5 + tid;
    int c = 0;
    while (__hip_atomic_load(fp1, __ATOMIC_RELAXED, __HIP_MEMORY_SCOPE_AGENT) != MAGIC64) {
      if (++c > SPIN_CAP) break;
      __builtin_amdgcn_s_sleep(8);
    }
  }
  __syncthreads();
  __builtin_amdgcn_fence(__ATOMIC_ACQUIRE, "agent");
  {
    const uint4* src = (const uint4*)((const char*)m2t + (size_t)h * 8192);
    ((uint4*)buf)[tid] = src[tid];
    ((uint4*)buf)[256 + tid] = src[256 + tid];
    if (tid < 64) {
      ((float*)(buf + 8192))[tid] = ksum[h * 64 + tid];
      ((float*)(buf + 8448))[tid] = bproj[tid];
    }
  }
  __syncthreads();
  u16* m2_l = (u16*)buf;
  float* ks_s = (float*)(buf + 8192);
  float* b_s = (float*)(buf + 8448);

  float ev[16];
  float mx = -INFINITY;
#pragma unroll
  for (int c4 = 0; c4 < 4; c4++) {
    float4 a = *(const float4*)(qr_g + quad * 16 + c4 * 4);
    ev[c4 * 4] = a.x; ev[c4 * 4 + 1] = a.y; ev[c4 * 4 + 2] = a.z; ev[c4 * 4 + 3] = a.w;
    mx = fmaxf(mx, fmaxf(fmaxf(a.x, a.y), fmaxf(a.z, a.w)));
  }
  mx = fmaxf(mx, __shfl_xor(mx, 16));
  mx = fmaxf(mx, __shfl_xor(mx, 32));
  float sum = 0.f, eks = 0.f;
#pragma unroll
  for (int j = 0; j < 16; j++) {
    float e = __expf(ev[j] - mx);
    ev[j] = e;
    sum += e;
    eks += e * ks_s[quad * 16 + j];
  }
  sum += __shfl_xor(sum, 16); sum += __shfl_xor(sum, 32);
  eks += __shfl_xor(eks, 16); eks += __shfl_xor(eks, 32);
  float invs = 1.0f / sum;
  float den = fmaf(eks, invs, 1e-6f);
  float scale = invs / den;
  uint4 e0v = make_uint4(pk2(ev[0], ev[1]), pk2(ev[2], ev[3]),
                         pk2(ev[4], ev[5]), pk2(ev[6], ev[7]));
  uint4 e1v = make_uint4(pk2(ev[8], ev[9]), pk2(ev[10], ev[11]),
                         pk2(ev[12], ev[13]), pk2(ev[14], ev[15]));
  *(uint4*)(p_b + lq * 128 + (((2 * quad) ^ (lq & 7)) * 16)) = e0v;
  *(uint4*)(p_b + lq * 128 + (((2 * quad + 1) ^ (lq & 7)) * 16)) = e1v;

  f4 oc[4];
  f4 zz2 = {0.f, 0.f, 0.f, 0.f};
#pragma unroll
  for (int et = 0; et < 4; et++) oc[et] = zz2;
  __builtin_amdgcn_s_setprio(1);
#pragma unroll
  for (int ks2 = 0; ks2 < 2; ks2++) {
    short8 ef = frag_row((const u16*)p_b, lq, 4 * ks2 + quad);
#pragma unroll
    for (int et = 0; et < 4; et++)
      oc[et] = MFMA_BF16(frag_row(m2_l, et * 16 + lq, 4 * ks2 + quad), ef, oc[et]);
  }
  __builtin_amdgcn_s_setprio(0);

  // ---- single write: out = o_s/l + o_l*scale + bias ----
  float invl = 1.0f / lrun;
  float* gp = out + ((size_t)(m * 64 + qrow)) * 1024 + h * 64 + quad * 4;
#pragma unroll
  for (int et = 0; et < 4; et++) {
    int e0 = et * 16 + quad * 4;
    float4 ov;
    ov.x = o[et][0] * invl + oc[et][0] * scale + b_s[e0 + 0];
    ov.y = o[et][1] * invl + oc[et][1] * scale + b_s[e0 + 1];
    ov.z = o[et][2] * invl + oc[et][2] * scale + b_s[e0 + 2];
    ov.w = o[et][3] * invl + oc[et][3] * scale + b_s[e0 + 3];
    *(float4*)(gp + et * 16) = ov;
  }
}

extern "C" void kernel_launch(void* const* d_in, const int* in_sizes, int n_in,
                              void* d_out, int out_size, void* d_ws, size_t ws_size,
                              hipStream_t stream) {
  const float* q = (const float*)d_in[0];
  const float* k = (const float*)d_in[1];
  const float* v = (const float*)d_in[2];
  const float* w = (const float*)d_in[3];
  const float* b = (const float*)d_in[4];
  float* out = (float*)d_out;

  // ws: kT 8MB u16 | vT 8MB u16 | kvp 16MB f32 | ksp 256KB f32 |
  //     kmv 256KB f32 | ksum 4KB f32 | m2t 128KB u16 | mf 640B u64
  u16* kT = (u16*)d_ws;
  u16* vT = kT + 4194304;
  float* kvp = (float*)(vT + 4194304);
  float* ksp = kvp + 4194304;
  float* kmv = ksp + 65536;
  float* ksum = kmv + 65536;
  u16* m2t = (u16*)(ksum + 1024);
  u64* mf = (u64*)(m2t + 65536);

  prep_kernel<<<1024, 256, 0, stream>>>(k, v, kT, vT, kvp, ksp, kmv);
  fusedpost_kernel<<<1024, 256, 0, stream>>>(q, kT, vT, kvp, ksp, kmv, w, b,
                                             m2t, ksum, mf, out);
}

// Round 7
// 208.615 us; speedup vs baseline: 4.3945x; 1.0101x over previous
//
#include <hip/hip_runtime.h>

// SparseLinearAttention: B=1, L=4096, H=16, D=64, BLKQ=BLKK=64, M=N=64, T=8.
// fp32 I/O. 2 dispatches:
//   prep(K one-pass: kT,kfmT,kvsum-partials,ksum-partials,km; V->vT)
// -> fusedpost: EVERY block (h,m) produces m2 column d=m (+ ksum[m]) from
//    kvp/ksp (~2-3us uniform, no straggler tail), releases flag pf[h][m];
//    then topk + K-loop; then RELAXED-poll the 64 flags of its head + one
//    acquire fence; then the linear part. (R6 lesson: concentrated producer
//    blocks = +70us serial tail. R5 lesson: no nontemporal anywhere.)

#define NH   16
#define DH   64
#define NBLK 64
#define TSEL 8

typedef unsigned short u16;
typedef unsigned int   u32;
typedef unsigned long long u64;
typedef __attribute__((ext_vector_type(8))) short short8;  // 8 bf16
typedef __attribute__((ext_vector_type(4))) float f4;
typedef __attribute__((ext_vector_type(4))) u32 u32x4;

#define MFMA_BF16(a, b, c) __builtin_amdgcn_mfma_f32_16x16x32_bf16(a, b, c, 0, 0, 0)
#define MAGIC64 0x2468ACE013579BDFull
#define SPIN_CAP 131072

__device__ __forceinline__ u16 f2bf_rne(float f) {
  u32 u = __float_as_uint(f);
  u += 0x7fffu + ((u >> 16) & 1u);
  return (u16)(u >> 16);
}
__device__ __forceinline__ u32 pk2(float a, float b) {
  return (u32)f2bf_rne(a) | ((u32)f2bf_rne(b) << 16);
}
__device__ __forceinline__ float bf2f(u16 u) { return __uint_as_float(((u32)u) << 16); }

// 8-bf16 fragment from a swizzled row-major bf16 tile (128B rows; logical
// 16B block j of row r stored at j^(r&7)).
__device__ __forceinline__ short8 frag_row(const u16* t, int row, int jblk) {
  return *(const short8*)((const char*)t + row * 128 + ((jblk ^ (row & 7)) * 16));
}

// ---------------- K_A: one-pass prep over K/V ------------------------------
// grid 1024 (XCD-swizzled: h = 2*(b&7) + (b>>9), n = (b>>3)&63), 256 thr.
__global__ __launch_bounds__(256) void prep_kernel(const float* __restrict__ k,
                                                   const float* __restrict__ v,
                                                   u16* __restrict__ kT,
                                                   u16* __restrict__ vT,
                                                   float* __restrict__ kvp,
                                                   float* __restrict__ ksp,
                                                   float* __restrict__ kmv) {
  __shared__ __align__(16) char vsl[8192];    // V^T bf16 swizzled
  __shared__ __align__(16) char kfm[8192];    // kfm^T bf16 swizzled
  __shared__ float kcol[64 * 65];             // raw K, column-major (km)
  __shared__ float redmx[256];
  __shared__ float redsm[256];
  __shared__ float kmred[256];
  __shared__ float ksred[256];
  int b = blockIdx.x;
  int n = (b >> 3) & 63;
  int h = 2 * (b & 7) + (b >> 9);
  int tid = threadIdx.x;
  int w = tid >> 6, lane = tid & 63;
  int row = lane, qd = w;
  int lq = lane & 15, quad = lane >> 4;

  // ---- K row segment (16 floats) ----
  float kv[16];
  {
    const float* kr = k + (size_t)(n * 64 + row) * 1024 + h * 64 + qd * 16;
#pragma unroll
    for (int c4 = 0; c4 < 4; c4++) {
      float4 a = *(const float4*)(kr + c4 * 4);
      kv[c4 * 4] = a.x; kv[c4 * 4 + 1] = a.y; kv[c4 * 4 + 2] = a.z; kv[c4 * 4 + 3] = a.w;
    }
  }
  // ---- kT global write (raw bf16, swizzled row layout) ----
  {
    char* ktb = (char*)(kT + ((size_t)(h * 64 + n)) * 4096);
    uint4 w0 = make_uint4(pk2(kv[0], kv[1]), pk2(kv[2], kv[3]),
                          pk2(kv[4], kv[5]), pk2(kv[6], kv[7]));
    uint4 w1 = make_uint4(pk2(kv[8], kv[9]), pk2(kv[10], kv[11]),
                          pk2(kv[12], kv[13]), pk2(kv[14], kv[15]));
    *(uint4*)(ktb + row * 128 + (((2 * qd) ^ (row & 7)) * 16)) = w0;
    *(uint4*)(ktb + row * 128 + (((2 * qd + 1) ^ (row & 7)) * 16)) = w1;
  }
  // ---- raw K into column-major LDS (for km) ----
  {
#pragma unroll
    for (int j = 0; j < 16; j++) kcol[(qd * 16 + j) * 65 + row] = kv[j];
  }
  // ---- V^T into LDS (scalar transpose scatter) ----
  {
    const float* vr = v + (size_t)(n * 64 + row) * 1024 + h * 64 + qd * 16;
    int kb = row >> 3, klo = row & 7;
#pragma unroll
    for (int c4 = 0; c4 < 4; c4++) {
      float4 a = *(const float4*)(vr + c4 * 4);
      float vv[4] = {a.x, a.y, a.z, a.w};
#pragma unroll
      for (int jj = 0; jj < 4; jj++) {
        int e = qd * 16 + c4 * 4 + jj;
        *(u16*)(vsl + e * 128 + ((kb ^ (e & 7)) * 16) + klo * 2) = f2bf_rne(vv[jj]);
      }
    }
  }
  // ---- row max partial ----
  {
    float mx = kv[0];
#pragma unroll
    for (int j = 1; j < 16; j++) mx = fmaxf(mx, kv[j]);
    redmx[qd * 64 + row] = mx;
  }
  __syncthreads();
  // ---- km partials ----
  {
    int c = tid & 63, g = tid >> 6;
    float pk = 0.f;
#pragma unroll
    for (int i = 0; i < 16; i++) pk += kcol[c * 65 + g * 16 + i];
    kmred[g * 64 + c] = pk;
  }
  // ---- row softmax: max fold + exp + sum partial ----
  {
    float mx = fmaxf(fmaxf(redmx[row], redmx[64 + row]),
                     fmaxf(redmx[128 + row], redmx[192 + row]));
    float sm = 0.f;
#pragma unroll
    for (int j = 0; j < 16; j++) { kv[j] = __expf(kv[j] - mx); sm += kv[j]; }
    redsm[qd * 64 + row] = sm;
  }
  __syncthreads();
  if (tid < 64)
    kmv[h * 4096 + n * 64 + tid] =
        (kmred[tid] + kmred[64 + tid] + kmred[128 + tid] + kmred[192 + tid]) * (1.0f / 64.0f);
  {
    float sm = redsm[row] + redsm[64 + row] + redsm[128 + row] + redsm[192 + row];
    float inv = 1.0f / sm;
    int rb = row >> 3, rlo = row & 7;
#pragma unroll
    for (int j = 0; j < 16; j++) {
      int d = qd * 16 + j;
      *(u16*)(kfm + d * 128 + (((rb) ^ (d & 7)) * 16) + rlo * 2) = f2bf_rne(kv[j] * inv);
    }
  }
  __syncthreads();   // kfm + vsl complete

  // ---- vT global copy ----
  {
    uint4* vt_out = (uint4*)(vT + ((size_t)(h * 64 + n)) * 4096);
    vt_out[tid] = ((const uint4*)vsl)[tid];
    vt_out[256 + tid] = ((const uint4*)vsl)[256 + tid];
  }
  // ---- ksum partial ----
  {
    float ks = 0.f;
    short8 x0 = frag_row((const u16*)kfm, lane, 2 * w);
    short8 x1 = frag_row((const u16*)kfm, lane, 2 * w + 1);
#pragma unroll
    for (int e = 0; e < 8; e++) ks += bf2f((u16)x0[e]) + bf2f((u16)x1[e]);
    ksred[tid] = ks;
  }
  // ---- kvsum MFMA partial -> plain global store ----
  {
    f4 acc[4];
    f4 zz = {0.f, 0.f, 0.f, 0.f};
#pragma unroll
    for (int et = 0; et < 4; et++) acc[et] = zz;
#pragma unroll
    for (int ks2 = 0; ks2 < 2; ks2++) {
      short8 a_ = frag_row((const u16*)kfm, w * 16 + lq, 4 * ks2 + quad);
#pragma unroll
      for (int et = 0; et < 4; et++)
        acc[et] = MFMA_BF16(a_, frag_row((const u16*)vsl, et * 16 + lq, 4 * ks2 + quad), acc[et]);
    }
    float* kvb = kvp + ((size_t)(h * 64 + n)) * 4096;
#pragma unroll
    for (int r = 0; r < 4; r++)
#pragma unroll
      for (int et = 0; et < 4; et++)
        kvb[(w * 16 + quad * 4 + r) * 64 + et * 16 + lq] = acc[et][r];
  }
  __syncthreads();
  if (tid < 64)
    ksp[((size_t)(h * 64 + n)) * 64 + tid] = ksred[tid] + ksred[64 + tid] +
                                             ksred[128 + tid] + ksred[192 + tid];
}

// ---------------- K_B: fusedpost (equal-spread producers) ------------------
// grid 1024 1D, XCD-swizzled. Block (h,m): PHASE A produces m2 column d=m
// and ksum[m] (~2-3us, uniform), releases pf[h*64+m]; PHASE B topk; PHASE C
// K-loop; PHASE D relaxed-poll 64 flags + acquire fence; linear part.
__global__ __launch_bounds__(256, 4) void fusedpost_kernel(const float* __restrict__ q,
                                                           const u16* __restrict__ kT,
                                                           const u16* __restrict__ vT,
                                                           const float* __restrict__ kvp,
                                                           const float* __restrict__ ksp,
                                                           const float* __restrict__ kmv,
                                                           const float* __restrict__ wgt,
                                                           const float* __restrict__ bproj,
                                                           u16* __restrict__ m2t,
                                                           float* __restrict__ ksum,
                                                           u64* __restrict__ pf,
                                                           float* __restrict__ out) {
  __shared__ __align__(16) char smem[24576];
  // producer era: wl[64*65]f32 @0 (16640B) | part[256]f32 @16640 | kvr[64] @17664
  // topk era:     km_s @0 (16640) | qmp @16640 | qmf @17664
  // K-loop era:   buf @0 (16K: K 8K + V^T 8K) | P @16384 (2K/wave)
  // linear era:   m2 @0 | ksum @8192 | bias @8448
  int b = blockIdx.x;
  int m = (b >> 3) & 63;
  int h = 2 * (b & 7) + (b >> 9);
  int tid = threadIdx.x, w = tid >> 6, lane = tid & 63;
  int lq = lane & 15, quad = lane >> 4;
  char* buf = smem;
  char* p_b = smem + 16384 + w * 2048;

  // ======= PHASE A: every block -> m2 column d=m + ksum[m] =======
  {
    float* wl = (float*)smem;              // W staged, stride 65
    float* part = (float*)(smem + 16640);  // 4 x 64 partials
    float* kvr = (float*)(smem + 17664);   // reduced kvsum row d=m
    int e = tid & 63, g = tid >> 6;
    // kvp n-partials: thread (e,g) sums n = g*16 .. g*16+15 of kvp[h][n][m*64+e]
    {
      const float* kb = kvp + (size_t)h * 64 * 4096 + m * 64 + e;
      float s = 0.f;
#pragma unroll
      for (int i = 0; i < 16; i++) s += kb[(size_t)(g * 16 + i) * 4096];
      part[g * 64 + e] = s;
    }
    // stage W (coalesced read, conflict-free LDS)
#pragma unroll
    for (int i = 0; i < 16; i++) {
      int f = i * 256 + tid;
      wl[(f >> 6) * 65 + (f & 63)] = wgt[f];
    }
    // ksum element m: wave 0, lane ln reads ksp[h][ln][m], butterfly-sum
    float kse = 0.f;
    if (tid < 64) {
      kse = ksp[(size_t)h * 64 * 64 + (size_t)tid * 64 + m];
#pragma unroll
      for (int off = 1; off < 64; off <<= 1) kse += __shfl_xor(kse, off);
    }
    __syncthreads();
    if (tid < 64) {
      kvr[tid] = (part[tid] + part[64 + tid]) + (part[128 + tid] + part[192 + tid]);
      if (tid == 0) ksum[h * 64 + m] = kse;
    }
    __syncthreads();
    // W multiply: thread (e,g) partial over j = g*16..+15
    {
      float acc = 0.f;
#pragma unroll
      for (int jj = 0; jj < 16; jj++)
        acc = fmaf(kvr[g * 16 + jj], wl[e * 65 + g * 16 + jj], acc);
      part[g * 64 + e] = acc;
    }
    __syncthreads();
    if (tid < 64) {
      float accf = (part[tid] + part[64 + tid]) + (part[128 + tid] + part[192 + tid]);
      int ee = tid, d = m;
      *(u16*)((char*)m2t + (size_t)h * 8192 + ee * 128 +
              (((d >> 3) ^ (ee & 7)) * 16) + (d & 7) * 2) = f2bf_rne(accf);
    }
    __syncthreads();
    if (tid == 0) {
      __threadfence();
      __hip_atomic_store(pf + h * 64 + m, MAGIC64, __ATOMIC_RELEASE,
                         __HIP_MEMORY_SCOPE_AGENT);
    }
    __syncthreads();   // LDS free for topk era
  }

  // ======= PHASE B: topk (q-block mean vs km, butterfly top-8) =======
  float* km_s = (float*)smem;
  float* qmp = (float*)(smem + 16640);
  float* qmf = (float*)(smem + 17664);
  {
    int c = tid & 63, g = tid >> 6;
    const float* qcol = q + ((size_t)(m * 64 + g * 16)) * 1024 + h * 64 + c;
    float qp = 0.f;
#pragma unroll
    for (int i = 0; i < 16; i++) qp += qcol[(size_t)i * 1024];
    qmp[g * 64 + c] = qp;
#pragma unroll
    for (int i = 0; i < 16; i++) {
      int idx = i * 256 + tid;
      km_s[(idx >> 6) * 65 + (idx & 63)] = kmv[h * 4096 + idx];
    }
  }
  __syncthreads();
  if (tid < 64) qmf[tid] = qmp[tid] + qmp[64 + tid] + qmp[128 + tid] + qmp[192 + tid];
  __syncthreads();
  int blks[8];
  {
    int n = lane;
    float s = 0.f;
#pragma unroll
    for (int d = 0; d < 64; d++) s += qmf[d] * km_s[n * 65 + d];
    float my = s;
#pragma unroll
    for (int t = 0; t < TSEL; t++) {
      float vv = my; int idx = n;
#pragma unroll
      for (int off = 1; off < 64; off <<= 1) {
        float ov = __shfl_xor(vv, off);
        int oi = __shfl_xor(idx, off);
        if (ov > vv || (ov == vv && oi < idx)) { vv = ov; idx = oi; }
      }
      int sel = __builtin_amdgcn_readfirstlane(idx);
      blks[t] = sel;
      if (n == sel) my = -INFINITY;
    }
  }
  __syncthreads();   // km_s dead

  // ======= PHASE C: block-sparse attention K-loop =======
  const int qrow = w * 16 + lq;
  const float* qr_g = q + ((size_t)(m * 64 + qrow)) * 1024 + h * 64;
  short8 qf[2];
#pragma unroll
  for (int ks = 0; ks < 2; ks++) {
    const float* gp = qr_g + (4 * ks + quad) * 8;
    float4 a = *(const float4*)gp;
    float4 bb = *(const float4*)(gp + 4);
    u32x4 tt = {pk2(a.x, a.y), pk2(a.z, a.w), pk2(bb.x, bb.y), pk2(bb.z, bb.w)};
    qf[ks] = __builtin_bit_cast(short8, tt);
  }

  { // stage K/V block 0
    const uint4* kt0 = (const uint4*)(kT + ((size_t)(h * 64 + blks[0])) * 4096);
    const uint4* vt0 = (const uint4*)(vT + ((size_t)(h * 64 + blks[0])) * 4096);
    ((uint4*)buf)[tid] = kt0[tid];
    ((uint4*)buf)[256 + tid] = kt0[256 + tid];
    ((uint4*)(buf + 8192))[tid] = vt0[tid];
    ((uint4*)(buf + 8192))[256 + tid] = vt0[256 + tid];
  }
  __syncthreads();

  float mrun = -INFINITY, lrun = 0.f;
  f4 o[4];
  f4 zz = {0.f, 0.f, 0.f, 0.f};
#pragma unroll
  for (int et = 0; et < 4; et++) o[et] = zz;

  const u16* kc = (const u16*)buf;
  const u16* vc = (const u16*)(buf + 8192);

  for (int t = 0; t < 8; t++) {
    uint4 pk0, pk1, pv0, pv1;
    if (t < 7) {
      const uint4* ktn = (const uint4*)(kT + ((size_t)(h * 64 + blks[t + 1])) * 4096);
      const uint4* vtn = (const uint4*)(vT + ((size_t)(h * 64 + blks[t + 1])) * 4096);
      pk0 = ktn[tid]; pk1 = ktn[256 + tid];
      pv0 = vtn[tid]; pv1 = vtn[256 + tid];
    }

    // S^T = K·Q^T
    f4 s[4];
#pragma unroll
    for (int kt = 0; kt < 4; kt++) s[kt] = zz;
    __builtin_amdgcn_s_setprio(1);
#pragma unroll
    for (int ks = 0; ks < 2; ks++)
#pragma unroll
      for (int kt = 0; kt < 4; kt++)
        s[kt] = MFMA_BF16(frag_row(kc, kt * 16 + lq, 4 * ks + quad), qf[ks], s[kt]);
    __builtin_amdgcn_s_setprio(0);

    // online softmax (16 scores/lane)
    float mp = -INFINITY;
#pragma unroll
    for (int kt = 0; kt < 4; kt++)
#pragma unroll
      for (int r = 0; r < 4; r++) mp = fmaxf(mp, s[kt][r]);
    mp = fmaxf(mp, __shfl_xor(mp, 16));
    mp = fmaxf(mp, __shfl_xor(mp, 32));
    mp *= 0.125f;
    if (__any(mp > mrun)) {
      float mn = fmaxf(mrun, mp);
      float al = __expf(mrun - mn);
      mrun = mn;
      lrun *= al;
#pragma unroll
      for (int et = 0; et < 4; et++)
#pragma unroll
        for (int r = 0; r < 4; r++) o[et][r] *= al;
    }
    float rs_ = 0.f;
#pragma unroll
    for (int kt = 0; kt < 4; kt++) {
      float p0 = __expf(fmaf(s[kt][0], 0.125f, -mrun));
      float p1 = __expf(fmaf(s[kt][1], 0.125f, -mrun));
      float p2 = __expf(fmaf(s[kt][2], 0.125f, -mrun));
      float p3 = __expf(fmaf(s[kt][3], 0.125f, -mrun));
      rs_ += p0 + p1 + p2 + p3;
      u32 lo32 = (__float_as_uint(p0) >> 16) | (__float_as_uint(p1) & 0xffff0000u);
      u32 hi32 = (__float_as_uint(p2) >> 16) | (__float_as_uint(p3) & 0xffff0000u);
      int addr = lq * 128 + (((kt * 2 + (quad >> 1)) ^ (lq & 7)) * 16) + (quad & 1) * 8;
      *(uint2*)(p_b + addr) = make_uint2(lo32, hi32);
    }
    rs_ += __shfl_xor(rs_, 16);
    rs_ += __shfl_xor(rs_, 32);
    lrun += rs_;

    // O^T += V^T · P^T
    __builtin_amdgcn_s_setprio(1);
#pragma unroll
    for (int ks = 0; ks < 2; ks++) {
      short8 pfr = frag_row((const u16*)p_b, lq, 4 * ks + quad);
#pragma unroll
      for (int et = 0; et < 4; et++)
        o[et] = MFMA_BF16(frag_row(vc, et * 16 + lq, 4 * ks + quad), pfr, o[et]);
    }
    __builtin_amdgcn_s_setprio(0);

    if (t < 7) {
      __syncthreads();
      ((uint4*)buf)[tid] = pk0;
      ((uint4*)buf)[256 + tid] = pk1;
      ((uint4*)(buf + 8192))[tid] = pv0;
      ((uint4*)(buf + 8192))[256 + tid] = pv1;
      __syncthreads();
    }
  }

  // ======= PHASE D: RELAXED-poll 64 flags + single acquire fence =======
  __syncthreads();
  if (tid < 64) {
    const u64* fp1 = pf + h * 64 + tid;
    int c = 0;
    while (__hip_atomic_load(fp1, __ATOMIC_RELAXED, __HIP_MEMORY_SCOPE_AGENT) != MAGIC64) {
      if (++c > SPIN_CAP) break;
      __builtin_amdgcn_s_sleep(8);
    }
  }
  __syncthreads();
  __builtin_amdgcn_fence(__ATOMIC_ACQUIRE, "agent");
  {
    const uint4* src = (const uint4*)((const char*)m2t + (size_t)h * 8192);
    ((uint4*)buf)[tid] = src[tid];
    ((uint4*)buf)[256 + tid] = src[256 + tid];
    if (tid < 64) {
      ((float*)(buf + 8192))[tid] = ksum[h * 64 + tid];
      ((float*)(buf + 8448))[tid] = bproj[tid];
    }
  }
  __syncthreads();
  u16* m2_l = (u16*)buf;
  float* ks_s = (float*)(buf + 8192);
  float* b_s = (float*)(buf + 8448);

  float ev[16];
  float mx = -INFINITY;
#pragma unroll
  for (int c4 = 0; c4 < 4; c4++) {
    float4 a = *(const float4*)(qr_g + quad * 16 + c4 * 4);
    ev[c4 * 4] = a.x; ev[c4 * 4 + 1] = a.y; ev[c4 * 4 + 2] = a.z; ev[c4 * 4 + 3] = a.w;
    mx = fmaxf(mx, fmaxf(fmaxf(a.x, a.y), fmaxf(a.z, a.w)));
  }
  mx = fmaxf(mx, __shfl_xor(mx, 16));
  mx = fmaxf(mx, __shfl_xor(mx, 32));
  float sum = 0.f, eks = 0.f;
#pragma unroll
  for (int j = 0; j < 16; j++) {
    float e = __expf(ev[j] - mx);
    ev[j] = e;
    sum += e;
    eks += e * ks_s[quad * 16 + j];
  }
  sum += __shfl_xor(sum, 16); sum += __shfl_xor(sum, 32);
  eks += __shfl_xor(eks, 16); eks += __shfl_xor(eks, 32);
  float invs = 1.0f / sum;
  float den = fmaf(eks, invs, 1e-6f);
  float scale = invs / den;
  uint4 e0v = make_uint4(pk2(ev[0], ev[1]), pk2(ev[2], ev[3]),
                         pk2(ev[4], ev[5]), pk2(ev[6], ev[7]));
  uint4 e1v = make_uint4(pk2(ev[8], ev[9]), pk2(ev[10], ev[11]),
                         pk2(ev[12], ev[13]), pk2(ev[14], ev[15]));
  *(uint4*)(p_b + lq * 128 + (((2 * quad) ^ (lq & 7)) * 16)) = e0v;
  *(uint4*)(p_b + lq * 128 + (((2 * quad + 1) ^ (lq & 7)) * 16)) = e1v;

  f4 oc[4];
  f4 zz2 = {0.f, 0.f, 0.f, 0.f};
#pragma unroll
  for (int et = 0; et < 4; et++) oc[et] = zz2;
  __builtin_amdgcn_s_setprio(1);
#pragma unroll
  for (int ks2 = 0; ks2 < 2; ks2++) {
    short8 ef = frag_row((const u16*)p_b, lq, 4 * ks2 + quad);
#pragma unroll
    for (int et = 0; et < 4; et++)
      oc[et] = MFMA_BF16(frag_row(m2_l, et * 16 + lq, 4 * ks2 + quad), ef, oc[et]);
  }
  __builtin_amdgcn_s_setprio(0);

  // ---- single write: out = o_s/l + o_l*scale + bias ----
  float invl = 1.0f / lrun;
  float* gp = out + ((size_t)(m * 64 + qrow)) * 1024 + h * 64 + quad * 4;
#pragma unroll
  for (int et = 0; et < 4; et++) {
    int e0 = et * 16 + quad * 4;
    float4 ov;
    ov.x = o[et][0] * invl + oc[et][0] * scale + b_s[e0 + 0];
    ov.y = o[et][1] * invl + oc[et][1] * scale + b_s[e0 + 1];
    ov.z = o[et][2] * invl + oc[et][2] * scale + b_s[e0 + 2];
    ov.w = o[et][3] * invl + oc[et][3] * scale + b_s[e0 + 3];
    *(float4*)(gp + et * 16) = ov;
  }
}

extern "C" void kernel_launch(void* const* d_in, const int* in_sizes, int n_in,
                              void* d_out, int out_size, void* d_ws, size_t ws_size,
                              hipStream_t stream) {
  const float* q = (const float*)d_in[0];
  const float* k = (const float*)d_in[1];
  const float* v = (const float*)d_in[2];
  const float* w = (const float*)d_in[3];
  const float* b = (const float*)d_in[4];
  float* out = (float*)d_out;

  // ws: kT 8MB u16 | vT 8MB u16 | kvp 16MB f32 | ksp 256KB f32 |
  //     kmv 256KB f32 | ksum 4KB f32 | m2t 128KB u16 | pf 8KB u64
  u16* kT = (u16*)d_ws;
  u16* vT = kT + 4194304;
  float* kvp = (float*)(vT + 4194304);
  float* ksp = kvp + 4194304;
  float* kmv = ksp + 65536;
  float* ksum = kmv + 65536;
  u16* m2t = (u16*)(ksum + 1024);
  u64* pf = (u64*)(m2t + 65536);

  prep_kernel<<<1024, 256, 0, stream>>>(k, v, kT, vT, kvp, ksp, kmv);
  fusedpost_kernel<<<1024, 256, 0, stream>>>(q, kT, vT, kvp, ksp, kmv, w, b,
                                             m2t, ksum, pf, out);
}

// Round 8
// 134.833 us; speedup vs baseline: 6.7992x; 1.5472x over previous
//
#include <hip/hip_runtime.h>

// SparseLinearAttention: B=1, L=4096, H=16, D=64, BLKQ=BLKK=64, M=N=64, T=8.
// fp32 I/O. 3 dispatches (R2 skeleton — no intra-kernel handoff; R7 lesson:
// agent-scope release/acquire at 1024-block scale costs ~80us in L2
// coherence ops):
//   prep(K one-pass: kT,kfmT,kvsum-partials,ksum-partials,km; V->vT)
//     -- rewritten with COLUMN passes: kfm^T/V^T built as contiguous
//        segments (2 uint4 stores) instead of 64+16 scalar LDS scatters.
// -> post(reduce kvsum partials + apply W -> m2; ksum)  [256 blocks]
// -> fused attn (topk in-block, XCD-swizzled, 24KB LDS -> 6 blk/CU).

#define NH   16
#define DH   64
#define NBLK 64
#define TSEL 8

typedef unsigned short u16;
typedef unsigned int   u32;
typedef __attribute__((ext_vector_type(8))) short short8;  // 8 bf16
typedef __attribute__((ext_vector_type(4))) float f4;
typedef __attribute__((ext_vector_type(4))) u32 u32x4;

#define MFMA_BF16(a, b, c) __builtin_amdgcn_mfma_f32_16x16x32_bf16(a, b, c, 0, 0, 0)

__device__ __forceinline__ u16 f2bf_rne(float f) {
  u32 u = __float_as_uint(f);
  u += 0x7fffu + ((u >> 16) & 1u);
  return (u16)(u >> 16);
}
__device__ __forceinline__ u32 pk2(float a, float b) {
  return (u32)f2bf_rne(a) | ((u32)f2bf_rne(b) << 16);
}
__device__ __forceinline__ float bf2f(u16 u) { return __uint_as_float(((u32)u) << 16); }

// 8-bf16 fragment from a swizzled row-major bf16 tile (128B rows; logical
// 16B block j of row r stored at j^(r&7)).
__device__ __forceinline__ short8 frag_row(const u16* t, int row, int jblk) {
  return *(const short8*)((const char*)t + row * 128 + ((jblk ^ (row & 7)) * 16));
}

// ---------------- K_A: one-pass prep over K/V (column-pass transposes) -----
// grid 1024 (XCD-swizzled: h = 2*(b&7) + (b>>9), n = (b>>3)&63), 256 thr.
__global__ __launch_bounds__(256) void prep_kernel(const float* __restrict__ k,
                                                   const float* __restrict__ v,
                                                   u16* __restrict__ kT,
                                                   u16* __restrict__ vT,
                                                   float* __restrict__ kvp,
                                                   float* __restrict__ ksp,
                                                   float* __restrict__ kmv) {
  __shared__ __align__(16) char vsl[8192];    // V^T bf16 swizzled
  __shared__ __align__(16) char kfm[8192];    // kfm^T bf16 swizzled
  __shared__ float kcol[64 * 65];             // raw K, column-major
  __shared__ float redmx[256];
  __shared__ float redsm[256];
  __shared__ float kmred[256];
  __shared__ float ksred[256];
  __shared__ float mxf[64];                   // folded row max
  __shared__ float smi[64];                   // folded 1/rowsum
  int b = blockIdx.x;
  int n = (b >> 3) & 63;
  int h = 2 * (b & 7) + (b >> 9);
  int tid = threadIdx.x;
  int w = tid >> 6, lane = tid & 63;
  int row = lane, qd = w;
  int lq = lane & 15, quad = lane >> 4;

  // ---- K row segment (16 floats), coalesced ----
  float kv[16];
  {
    const float* kr = k + (size_t)(n * 64 + row) * 1024 + h * 64 + qd * 16;
#pragma unroll
    for (int c4 = 0; c4 < 4; c4++) {
      float4 a = *(const float4*)(kr + c4 * 4);
      kv[c4 * 4] = a.x; kv[c4 * 4 + 1] = a.y; kv[c4 * 4 + 2] = a.z; kv[c4 * 4 + 3] = a.w;
    }
  }
  // ---- kT global write (raw bf16, swizzled row layout) ----
  {
    char* ktb = (char*)(kT + ((size_t)(h * 64 + n)) * 4096);
    uint4 w0 = make_uint4(pk2(kv[0], kv[1]), pk2(kv[2], kv[3]),
                          pk2(kv[4], kv[5]), pk2(kv[6], kv[7]));
    uint4 w1 = make_uint4(pk2(kv[8], kv[9]), pk2(kv[10], kv[11]),
                          pk2(kv[12], kv[13]), pk2(kv[14], kv[15]));
    *(uint4*)(ktb + row * 128 + (((2 * qd) ^ (row & 7)) * 16)) = w0;
    *(uint4*)(ktb + row * 128 + (((2 * qd + 1) ^ (row & 7)) * 16)) = w1;
  }
  // ---- raw K into column-major LDS ----
  {
#pragma unroll
    for (int j = 0; j < 16; j++) kcol[(qd * 16 + j) * 65 + row] = kv[j];
  }
  // ---- row max partial ----
  {
    float mx = kv[0];
#pragma unroll
    for (int j = 1; j < 16; j++) mx = fmaxf(mx, kv[j]);
    redmx[qd * 64 + row] = mx;
  }
  __syncthreads();   // B1: kcol + redmx ready
  // ---- km partials ----
  {
    int c = tid & 63, g = tid >> 6;
    float pk = 0.f;
#pragma unroll
    for (int i = 0; i < 16; i++) pk += kcol[c * 65 + g * 16 + i];
    kmred[g * 64 + c] = pk;
  }
  // ---- row pass: max fold + exp-sum partial (exps not kept) ----
  {
    float mx = fmaxf(fmaxf(redmx[row], redmx[64 + row]),
                     fmaxf(redmx[128 + row], redmx[192 + row]));
    float sm = 0.f;
#pragma unroll
    for (int j = 0; j < 16; j++) sm += __expf(kv[j] - mx);
    redsm[qd * 64 + row] = sm;
  }
  __syncthreads();   // B2: kmred + redsm ready
  if (tid < 64) {
    kmv[h * 4096 + n * 64 + tid] =
        (kmred[tid] + kmred[64 + tid] + kmred[128 + tid] + kmred[192 + tid]) * (1.0f / 64.0f);
    mxf[tid] = fmaxf(fmaxf(redmx[tid], redmx[64 + tid]),
                     fmaxf(redmx[128 + tid], redmx[192 + tid]));
    smi[tid] = 1.0f / (redsm[tid] + redsm[64 + tid] + redsm[128 + tid] + redsm[192 + tid]);
  }
  __syncthreads();   // B3: mxf/smi ready

  // ---- column pass kfm^T: thread (c=lane, g=w) owns row c, k in [16g,16g+16) ----
  {
    int c = lane, g = w;
    float e[16];
#pragma unroll
    for (int i = 0; i < 16; i++) {
      int r = g * 16 + i;
      e[i] = __expf(kcol[c * 65 + r] - mxf[r]) * smi[r];
    }
    uint4 x0 = make_uint4(pk2(e[0], e[1]), pk2(e[2], e[3]),
                          pk2(e[4], e[5]), pk2(e[6], e[7]));
    uint4 x1 = make_uint4(pk2(e[8], e[9]), pk2(e[10], e[11]),
                          pk2(e[12], e[13]), pk2(e[14], e[15]));
    *(uint4*)(kfm + c * 128 + (((2 * g) ^ (c & 7)) * 16)) = x0;
    *(uint4*)(kfm + c * 128 + (((2 * g + 1) ^ (c & 7)) * 16)) = x1;
  }
  // ---- column pass V^T: coalesced column reads -> 2 vector LDS stores ----
  {
    int c = lane, g = w;
    const float* vcol = v + (size_t)(n * 64 + g * 16) * 1024 + h * 64 + c;
    float vv[16];
#pragma unroll
    for (int i = 0; i < 16; i++) vv[i] = vcol[(size_t)i * 1024];
    uint4 x0 = make_uint4(pk2(vv[0], vv[1]), pk2(vv[2], vv[3]),
                          pk2(vv[4], vv[5]), pk2(vv[6], vv[7]));
    uint4 x1 = make_uint4(pk2(vv[8], vv[9]), pk2(vv[10], vv[11]),
                          pk2(vv[12], vv[13]), pk2(vv[14], vv[15]));
    *(uint4*)(vsl + c * 128 + (((2 * g) ^ (c & 7)) * 16)) = x0;
    *(uint4*)(vsl + c * 128 + (((2 * g + 1) ^ (c & 7)) * 16)) = x1;
  }
  __syncthreads();   // B4: kfm + vsl complete

  // ---- vT global copy (coalesced) ----
  {
    uint4* vt_out = (uint4*)(vT + ((size_t)(h * 64 + n)) * 4096);
    vt_out[tid] = ((const uint4*)vsl)[tid];
    vt_out[256 + tid] = ((const uint4*)vsl)[256 + tid];
  }
  // ---- ksum partial: wave w sums key-blocks jb=2w,2w+1 over d=lane ----
  {
    float ks = 0.f;
    short8 x0 = frag_row((const u16*)kfm, lane, 2 * w);
    short8 x1 = frag_row((const u16*)kfm, lane, 2 * w + 1);
#pragma unroll
    for (int e = 0; e < 8; e++) ks += bf2f((u16)x0[e]) + bf2f((u16)x1[e]);
    ksred[tid] = ks;
  }
  // ---- kvsum MFMA partial -> plain global store ----
  {
    f4 acc[4];
    f4 zz = {0.f, 0.f, 0.f, 0.f};
#pragma unroll
    for (int et = 0; et < 4; et++) acc[et] = zz;
#pragma unroll
    for (int ks2 = 0; ks2 < 2; ks2++) {
      short8 a_ = frag_row((const u16*)kfm, w * 16 + lq, 4 * ks2 + quad);
#pragma unroll
      for (int et = 0; et < 4; et++)
        acc[et] = MFMA_BF16(a_, frag_row((const u16*)vsl, et * 16 + lq, 4 * ks2 + quad), acc[et]);
    }
    float* kvb = kvp + ((size_t)(h * 64 + n)) * 4096;
#pragma unroll
    for (int r = 0; r < 4; r++)
#pragma unroll
      for (int et = 0; et < 4; et++)
        kvb[(w * 16 + quad * 4 + r) * 64 + et * 16 + lq] = acc[et][r];
  }
  __syncthreads();
  if (tid < 64)
    ksp[((size_t)(h * 64 + n)) * 64 + tid] = ksred[tid] + ksred[64 + tid] +
                                             ksred[128 + tid] + ksred[192 + tid];
}

// ---------------- K_B: post — reduce kvsum partials + apply W -> m2 --------
// grid 256: block (h = bx>>4, dq = bx&15) owns d-rows [dq*4, dq*4+4).
__global__ __launch_bounds__(256) void post_kernel(const float* __restrict__ kvp,
                                                   const float* __restrict__ ksp,
                                                   const float* __restrict__ wgt,
                                                   u16* __restrict__ m2t,
                                                   float* __restrict__ ksum) {
  __shared__ float kr[4][64];
  __shared__ float wl[64 * 65];   // wl[e*65 + j] = W[e][j]
  int bx = blockIdx.x, tid = threadIdx.x;
  int h = bx >> 4, dq = bx & 15;
  int j = tid & 63, rr = tid >> 6;

  // reduce kvsum row (dq*4+rr), col j over 64 n-partials
  {
    size_t off = (size_t)(dq * 4 + rr) * 64 + j;
    const float* base = kvp + (size_t)h * 64 * 4096 + off;
    float s0 = 0.f, s1 = 0.f, s2 = 0.f, s3 = 0.f;
#pragma unroll
    for (int n4 = 0; n4 < 16; n4++) {
      s0 += base[(size_t)(n4 * 4 + 0) * 4096];
      s1 += base[(size_t)(n4 * 4 + 1) * 4096];
      s2 += base[(size_t)(n4 * 4 + 2) * 4096];
      s3 += base[(size_t)(n4 * 4 + 3) * 4096];
    }
    kr[rr][j] = (s0 + s1) + (s2 + s3);
  }
  // stage W (coalesced read, conflict-free LDS)
#pragma unroll
  for (int i = 0; i < 16; i++) {
    int f = i * 256 + tid;
    wl[(f >> 6) * 65 + (f & 63)] = wgt[f];
  }
  __syncthreads();

  // m2[e][d] slice: thread (rr2 = tid>>6, e = tid&63), d = dq*4+rr2
  {
    int e = tid & 63, rr2 = tid >> 6;
    float acc = 0.f;
#pragma unroll
    for (int jj = 0; jj < 64; jj++) acc = fmaf(kr[rr2][jj], wl[e * 65 + jj], acc);
    int d = dq * 4 + rr2;
    *(u16*)((char*)m2t + (size_t)h * 8192 + e * 128 +
            (((d >> 3) ^ (e & 7)) * 16) + (d & 7) * 2) = f2bf_rne(acc);
  }
  // ksum reduction (once per h)
  if (dq == 0 && tid < 64) {
    const float* base = ksp + (size_t)h * 64 * 64 + tid;
    float s = 0.f;
#pragma unroll
    for (int n = 0; n < 64; n++) s += base[(size_t)n * 64];
    ksum[h * 64 + tid] = s;
  }
}

// ---------------- K_C: fused topk + block-sparse + linear attention --------
// grid 1024 1D, XCD-swizzled (each XCD owns 2 heads -> kT/vT/km L2-local).
// 256 thr = 4 waves; wave w owns Q rows [w*16, w*16+16). Per-block topk
// (q-block mean vs km, butterfly argmax, tie->lower idx). Q fragments load
// straight from global (no Q LDS) -> 24 KB LDS -> 6 blocks/CU.
__global__ __launch_bounds__(256, 6) void fused_attn_kernel(const float* __restrict__ q,
                                                            const u16* __restrict__ kT,
                                                            const u16* __restrict__ vT,
                                                            const float* __restrict__ kmv,
                                                            const u16* __restrict__ m2t,
                                                            const float* __restrict__ ksum,
                                                            const float* __restrict__ bproj,
                                                            float* __restrict__ out) {
  __shared__ __align__(16) char smem[24576];
  // K-loop era: [0,8K) K | [8K,16K) V^T | [16K,24K) P (2K/wave)
  // topk era:   [0,16.6K) km padded | [20K..] qm scratch
  // post-loop:  [0,8K) m2 | [8K..) ksum/bias
  int b = blockIdx.x;
  int m = (b >> 3) & 63;
  int h = 2 * (b & 7) + (b >> 9);
  int tid = threadIdx.x, w = tid >> 6, lane = tid & 63;
  int lq = lane & 15, quad = lane >> 4;
  char* buf = smem;
  char* p_b = smem + 16384 + w * 2048;
  float* km_s = (float*)smem;             // stride 65
  float* qmp = (float*)(smem + 20480);    // 256 floats
  float* qmf = (float*)(smem + 21504);    // 64 floats

  // ---- topk phase: q-block mean + scores vs km + butterfly top-8 ----
  {
    int c = tid & 63, g = tid >> 6;
    const float* qcol = q + ((size_t)(m * 64 + g * 16)) * 1024 + h * 64 + c;
    float qp = 0.f;
#pragma unroll
    for (int i = 0; i < 16; i++) qp += qcol[(size_t)i * 1024];
    qmp[g * 64 + c] = qp;
#pragma unroll
    for (int i = 0; i < 16; i++) {
      int idx = i * 256 + tid;
      km_s[(idx >> 6) * 65 + (idx & 63)] = kmv[h * 4096 + idx];
    }
  }
  __syncthreads();
  if (tid < 64) qmf[tid] = qmp[tid] + qmp[64 + tid] + qmp[128 + tid] + qmp[192 + tid];
  __syncthreads();
  int blks[8];
  {
    int n = lane;
    float s = 0.f;
#pragma unroll
    for (int d = 0; d < 64; d++) s += qmf[d] * km_s[n * 65 + d];
    float my = s;
#pragma unroll
    for (int t = 0; t < TSEL; t++) {
      float vv = my; int idx = n;
#pragma unroll
      for (int off = 1; off < 64; off <<= 1) {
        float ov = __shfl_xor(vv, off);
        int oi = __shfl_xor(idx, off);
        if (ov > vv || (ov == vv && oi < idx)) { vv = ov; idx = oi; }
      }
      int sel = __builtin_amdgcn_readfirstlane(idx);
      blks[t] = sel;
      if (n == sel) my = -INFINITY;
    }
  }
  __syncthreads();   // km_s dead; buf reusable

  // ---- Q fragments straight from global (bf16 pack in-reg) ----
  const int qrow = w * 16 + lq;
  const float* qr_g = q + ((size_t)(m * 64 + qrow)) * 1024 + h * 64;
  short8 qf[2];
#pragma unroll
  for (int ks = 0; ks < 2; ks++) {
    const float* gp = qr_g + (4 * ks + quad) * 8;
    float4 a = *(const float4*)gp;
    float4 bb = *(const float4*)(gp + 4);
    u32x4 tt = {pk2(a.x, a.y), pk2(a.z, a.w), pk2(bb.x, bb.y), pk2(bb.z, bb.w)};
    qf[ks] = __builtin_bit_cast(short8, tt);
  }

  { // stage K/V block 0
    const uint4* kt0 = (const uint4*)(kT + ((size_t)(h * 64 + blks[0])) * 4096);
    const uint4* vt0 = (const uint4*)(vT + ((size_t)(h * 64 + blks[0])) * 4096);
    ((uint4*)buf)[tid] = kt0[tid];
    ((uint4*)buf)[256 + tid] = kt0[256 + tid];
    ((uint4*)(buf + 8192))[tid] = vt0[tid];
    ((uint4*)(buf + 8192))[256 + tid] = vt0[256 + tid];
  }
  __syncthreads();

  float mrun = -INFINITY, lrun = 0.f;
  f4 o[4];
  f4 zz = {0.f, 0.f, 0.f, 0.f};
#pragma unroll
  for (int et = 0; et < 4; et++) o[et] = zz;

  const u16* kc = (const u16*)buf;
  const u16* vc = (const u16*)(buf + 8192);

  for (int t = 0; t < 8; t++) {
    // issue next-tile prefetch (16 transient VGPRs)
    uint4 pk0, pk1, pv0, pv1;
    if (t < 7) {
      const uint4* ktn = (const uint4*)(kT + ((size_t)(h * 64 + blks[t + 1])) * 4096);
      const uint4* vtn = (const uint4*)(vT + ((size_t)(h * 64 + blks[t + 1])) * 4096);
      pk0 = ktn[tid]; pk1 = ktn[256 + tid];
      pv0 = vtn[tid]; pv1 = vtn[256 + tid];
    }

    // S^T = K·Q^T
    f4 s[4];
#pragma unroll
    for (int kt = 0; kt < 4; kt++) s[kt] = zz;
    __builtin_amdgcn_s_setprio(1);
#pragma unroll
    for (int ks = 0; ks < 2; ks++)
#pragma unroll
      for (int kt = 0; kt < 4; kt++)
        s[kt] = MFMA_BF16(frag_row(kc, kt * 16 + lq, 4 * ks + quad), qf[ks], s[kt]);
    __builtin_amdgcn_s_setprio(0);

    // online softmax (16 scores/lane), P row lq -> wave-private slab
    float mp = -INFINITY;
#pragma unroll
    for (int kt = 0; kt < 4; kt++)
#pragma unroll
      for (int r = 0; r < 4; r++) mp = fmaxf(mp, s[kt][r]);
    mp = fmaxf(mp, __shfl_xor(mp, 16));
    mp = fmaxf(mp, __shfl_xor(mp, 32));
    mp *= 0.125f;
    // exact defer: lut is score-descending, so later tiles rarely raise the
    // max -> skip the rescale pass entirely when no lane's max grows.
    if (__any(mp > mrun)) {
      float mn = fmaxf(mrun, mp);
      float al = __expf(mrun - mn);
      mrun = mn;
      lrun *= al;
#pragma unroll
      for (int et = 0; et < 4; et++)
#pragma unroll
        for (int r = 0; r < 4; r++) o[et][r] *= al;
    }
    float rs_ = 0.f;
#pragma unroll
    for (int kt = 0; kt < 4; kt++) {
      float p0 = __expf(fmaf(s[kt][0], 0.125f, -mrun));
      float p1 = __expf(fmaf(s[kt][1], 0.125f, -mrun));
      float p2 = __expf(fmaf(s[kt][2], 0.125f, -mrun));
      float p3 = __expf(fmaf(s[kt][3], 0.125f, -mrun));
      rs_ += p0 + p1 + p2 + p3;
      u32 lo32 = (__float_as_uint(p0) >> 16) | (__float_as_uint(p1) & 0xffff0000u);
      u32 hi32 = (__float_as_uint(p2) >> 16) | (__float_as_uint(p3) & 0xffff0000u);
      int addr = lq * 128 + (((kt * 2 + (quad >> 1)) ^ (lq & 7)) * 16) + (quad & 1) * 8;
      *(uint2*)(p_b + addr) = make_uint2(lo32, hi32);
    }
    rs_ += __shfl_xor(rs_, 16);
    rs_ += __shfl_xor(rs_, 32);
    lrun += rs_;

    // O^T += V^T · P^T
    __builtin_amdgcn_s_setprio(1);
#pragma unroll
    for (int ks = 0; ks < 2; ks++) {
      short8 pf = frag_row((const u16*)p_b, lq, 4 * ks + quad);
#pragma unroll
      for (int et = 0; et < 4; et++)
        o[et] = MFMA_BF16(frag_row(vc, et * 16 + lq, 4 * ks + quad), pf, o[et]);
    }
    __builtin_amdgcn_s_setprio(0);

    // rotate buffer: wait for all readers, drain prefetch, publish
    if (t < 7) {
      __syncthreads();
      ((uint4*)buf)[tid] = pk0;
      ((uint4*)buf)[256 + tid] = pk1;
      ((uint4*)(buf + 8192))[tid] = pv0;
      ((uint4*)(buf + 8192))[256 + tid] = pv1;
      __syncthreads();
    }
  }

  // ---- stage m2 + ksum + bias into buf (reuse), then fused linear attn ----
  __syncthreads();
  {
    const uint4* src = (const uint4*)((const char*)m2t + (size_t)h * 8192);
    ((uint4*)buf)[tid] = src[tid];
    ((uint4*)buf)[256 + tid] = src[256 + tid];
    if (tid < 64) {
      ((float*)(buf + 8192))[tid] = ksum[h * 64 + tid];
      ((float*)(buf + 8448))[tid] = bproj[tid];
    }
  }
  __syncthreads();
  u16* m2_l = (u16*)buf;
  float* ks_s = (float*)(buf + 8192);
  float* b_s = (float*)(buf + 8448);

  // linear-attn feature map from fp32 q row (cols quad*16..+16)
  float ev[16];
  float mx = -INFINITY;
#pragma unroll
  for (int c4 = 0; c4 < 4; c4++) {
    float4 a = *(const float4*)(qr_g + quad * 16 + c4 * 4);
    ev[c4 * 4] = a.x; ev[c4 * 4 + 1] = a.y; ev[c4 * 4 + 2] = a.z; ev[c4 * 4 + 3] = a.w;
    mx = fmaxf(mx, fmaxf(fmaxf(a.x, a.y), fmaxf(a.z, a.w)));
  }
  mx = fmaxf(mx, __shfl_xor(mx, 16));
  mx = fmaxf(mx, __shfl_xor(mx, 32));
  float sum = 0.f, eks = 0.f;
#pragma unroll
  for (int j = 0; j < 16; j++) {
    float e = __expf(ev[j] - mx);
    ev[j] = e;
    sum += e;
    eks += e * ks_s[quad * 16 + j];
  }
  sum += __shfl_xor(sum, 16); sum += __shfl_xor(sum, 32);
  eks += __shfl_xor(eks, 16); eks += __shfl_xor(eks, 32);
  float invs = 1.0f / sum;
  float den = fmaf(eks, invs, 1e-6f);
  float scale = invs / den;
  // E row lq -> wave slab (blocks 2*quad, 2*quad+1)
  uint4 e0v = make_uint4(pk2(ev[0], ev[1]), pk2(ev[2], ev[3]),
                         pk2(ev[4], ev[5]), pk2(ev[6], ev[7]));
  uint4 e1v = make_uint4(pk2(ev[8], ev[9]), pk2(ev[10], ev[11]),
                         pk2(ev[12], ev[13]), pk2(ev[14], ev[15]));
  *(uint4*)(p_b + lq * 128 + (((2 * quad) ^ (lq & 7)) * 16)) = e0v;
  *(uint4*)(p_b + lq * 128 + (((2 * quad + 1) ^ (lq & 7)) * 16)) = e1v;

  f4 oc[4];
  f4 zz2 = {0.f, 0.f, 0.f, 0.f};
#pragma unroll
  for (int et = 0; et < 4; et++) oc[et] = zz2;
  __builtin_amdgcn_s_setprio(1);
#pragma unroll
  for (int ks2 = 0; ks2 < 2; ks2++) {
    short8 ef = frag_row((const u16*)p_b, lq, 4 * ks2 + quad);
#pragma unroll
    for (int et = 0; et < 4; et++)
      oc[et] = MFMA_BF16(frag_row(m2_l, et * 16 + lq, 4 * ks2 + quad), ef, oc[et]);
  }
  __builtin_amdgcn_s_setprio(0);

  // ---- single write: out = o_s/l + o_l*scale + bias ----
  float invl = 1.0f / lrun;
  float* gp = out + ((size_t)(m * 64 + qrow)) * 1024 + h * 64 + quad * 4;
#pragma unroll
  for (int et = 0; et < 4; et++) {
    int e0 = et * 16 + quad * 4;
    float4 ov;
    ov.x = o[et][0] * invl + oc[et][0] * scale + b_s[e0 + 0];
    ov.y = o[et][1] * invl + oc[et][1] * scale + b_s[e0 + 1];
    ov.z = o[et][2] * invl + oc[et][2] * scale + b_s[e0 + 2];
    ov.w = o[et][3] * invl + oc[et][3] * scale + b_s[e0 + 3];
    *(float4*)(gp + et * 16) = ov;
  }
}

extern "C" void kernel_launch(void* const* d_in, const int* in_sizes, int n_in,
                              void* d_out, int out_size, void* d_ws, size_t ws_size,
                              hipStream_t stream) {
  const float* q = (const float*)d_in[0];
  const float* k = (const float*)d_in[1];
  const float* v = (const float*)d_in[2];
  const float* w = (const float*)d_in[3];
  const float* b = (const float*)d_in[4];
  float* out = (float*)d_out;

  // ws: kT 8MB u16 | vT 8MB u16 | kvp 16MB f32 | ksp 256KB f32 |
  //     kmv 256KB f32 | ksum 4KB f32 | m2t 128KB u16   (~32.6MB of 256MB)
  u16* kT = (u16*)d_ws;
  u16* vT = kT + 4194304;
  float* kvp = (float*)(vT + 4194304);
  float* ksp = kvp + 4194304;
  float* kmv = ksp + 65536;
  float* ksum = kmv + 65536;
  u16* m2t = (u16*)(ksum + 1024);

  prep_kernel<<<1024, 256, 0, stream>>>(k, v, kT, vT, kvp, ksp, kmv);
  post_kernel<<<256, 256, 0, stream>>>(kvp, ksp, w, m2t, ksum);
  fused_attn_kernel<<<1024, 256, 0, stream>>>(q, kT, vT, kmv, m2t, ksum, b, out);
}

// Round 9
// 131.857 us; speedup vs baseline: 6.9527x; 1.0226x over previous
//
#include <hip/hip_runtime.h>

// SparseLinearAttention: B=1, L=4096, H=16, D=64, BLKQ=BLKK=64, M=N=64, T=8.
// fp32 I/O. 3 dispatches (R2 skeleton; R7 lesson: no intra-kernel handoff):
//   prep (column-pass transposes)  [unchanged from R8]
// -> post (reduce kvp + apply W)   [unchanged from R8]
// -> fused attn: K-loop now DOUBLE-BUFFERED with global_load_lds async
//    staging -> 1 barrier/iter (was 2 + reg round-trip). 40KB LDS ->
//    4 blk/CU exact fit (1024 blocks all co-resident).

#define NH   16
#define DH   64
#define NBLK 64
#define TSEL 8

typedef unsigned short u16;
typedef unsigned int   u32;
typedef __attribute__((ext_vector_type(8))) short short8;  // 8 bf16
typedef __attribute__((ext_vector_type(4))) float f4;
typedef __attribute__((ext_vector_type(4))) u32 u32x4;

#define MFMA_BF16(a, b, c) __builtin_amdgcn_mfma_f32_16x16x32_bf16(a, b, c, 0, 0, 0)

__device__ __forceinline__ u16 f2bf_rne(float f) {
  u32 u = __float_as_uint(f);
  u += 0x7fffu + ((u >> 16) & 1u);
  return (u16)(u >> 16);
}
__device__ __forceinline__ u32 pk2(float a, float b) {
  return (u32)f2bf_rne(a) | ((u32)f2bf_rne(b) << 16);
}
__device__ __forceinline__ float bf2f(u16 u) { return __uint_as_float(((u32)u) << 16); }

// 8-bf16 fragment from a swizzled row-major bf16 tile (128B rows; logical
// 16B block j of row r stored at j^(r&7)).
__device__ __forceinline__ short8 frag_row(const u16* t, int row, int jblk) {
  return *(const short8*)((const char*)t + row * 128 + ((jblk ^ (row & 7)) * 16));
}

// async global->LDS, 16B per lane (wave-uniform base + lane*16 layout).
__device__ __forceinline__ void gload_lds16(const char* g, char* l) {
  __builtin_amdgcn_global_load_lds(
      (const __attribute__((address_space(1))) char*)g,
      (__attribute__((address_space(3))) char*)l, 16, 0, 0);
}

// stage one K/V tile pair (8KB + 8KB) into dst (K@0, V@8192).
// wave 0: K[0,4K) w1: K[4K,8K) w2: V[0,4K) w3: V[4K,8K); 4 x 1KB insts each.
__device__ __forceinline__ void stage_async(const char* ktb, const char* vtb,
                                            char* dst, int w, int lane) {
  const char* s = ((w & 2) ? vtb : ktb) + (w & 1) * 4096 + lane * 16;
  char* d = dst + ((w & 2) ? 8192 : 0) + (w & 1) * 4096 + lane * 16;
#pragma unroll
  for (int i = 0; i < 4; i++) gload_lds16(s + i * 1024, d + i * 1024);
}

// ---------------- K_A: one-pass prep over K/V (column-pass transposes) -----
// grid 1024 (XCD-swizzled: h = 2*(b&7) + (b>>9), n = (b>>3)&63), 256 thr.
__global__ __launch_bounds__(256) void prep_kernel(const float* __restrict__ k,
                                                   const float* __restrict__ v,
                                                   u16* __restrict__ kT,
                                                   u16* __restrict__ vT,
                                                   float* __restrict__ kvp,
                                                   float* __restrict__ ksp,
                                                   float* __restrict__ kmv) {
  __shared__ __align__(16) char vsl[8192];    // V^T bf16 swizzled
  __shared__ __align__(16) char kfm[8192];    // kfm^T bf16 swizzled
  __shared__ float kcol[64 * 65];             // raw K, column-major
  __shared__ float redmx[256];
  __shared__ float redsm[256];
  __shared__ float kmred[256];
  __shared__ float ksred[256];
  __shared__ float mxf[64];                   // folded row max
  __shared__ float smi[64];                   // folded 1/rowsum
  int b = blockIdx.x;
  int n = (b >> 3) & 63;
  int h = 2 * (b & 7) + (b >> 9);
  int tid = threadIdx.x;
  int w = tid >> 6, lane = tid & 63;
  int row = lane, qd = w;
  int lq = lane & 15, quad = lane >> 4;

  // ---- K row segment (16 floats), coalesced ----
  float kv[16];
  {
    const float* kr = k + (size_t)(n * 64 + row) * 1024 + h * 64 + qd * 16;
#pragma unroll
    for (int c4 = 0; c4 < 4; c4++) {
      float4 a = *(const float4*)(kr + c4 * 4);
      kv[c4 * 4] = a.x; kv[c4 * 4 + 1] = a.y; kv[c4 * 4 + 2] = a.z; kv[c4 * 4 + 3] = a.w;
    }
  }
  // ---- kT global write (raw bf16, swizzled row layout) ----
  {
    char* ktb = (char*)(kT + ((size_t)(h * 64 + n)) * 4096);
    uint4 w0 = make_uint4(pk2(kv[0], kv[1]), pk2(kv[2], kv[3]),
                          pk2(kv[4], kv[5]), pk2(kv[6], kv[7]));
    uint4 w1 = make_uint4(pk2(kv[8], kv[9]), pk2(kv[10], kv[11]),
                          pk2(kv[12], kv[13]), pk2(kv[14], kv[15]));
    *(uint4*)(ktb + row * 128 + (((2 * qd) ^ (row & 7)) * 16)) = w0;
    *(uint4*)(ktb + row * 128 + (((2 * qd + 1) ^ (row & 7)) * 16)) = w1;
  }
  // ---- raw K into column-major LDS ----
  {
#pragma unroll
    for (int j = 0; j < 16; j++) kcol[(qd * 16 + j) * 65 + row] = kv[j];
  }
  // ---- row max partial ----
  {
    float mx = kv[0];
#pragma unroll
    for (int j = 1; j < 16; j++) mx = fmaxf(mx, kv[j]);
    redmx[qd * 64 + row] = mx;
  }
  __syncthreads();   // B1: kcol + redmx ready
  // ---- km partials ----
  {
    int c = tid & 63, g = tid >> 6;
    float pk = 0.f;
#pragma unroll
    for (int i = 0; i < 16; i++) pk += kcol[c * 65 + g * 16 + i];
    kmred[g * 64 + c] = pk;
  }
  // ---- row pass: max fold + exp-sum partial (exps not kept) ----
  {
    float mx = fmaxf(fmaxf(redmx[row], redmx[64 + row]),
                     fmaxf(redmx[128 + row], redmx[192 + row]));
    float sm = 0.f;
#pragma unroll
    for (int j = 0; j < 16; j++) sm += __expf(kv[j] - mx);
    redsm[qd * 64 + row] = sm;
  }
  __syncthreads();   // B2: kmred + redsm ready
  if (tid < 64) {
    kmv[h * 4096 + n * 64 + tid] =
        (kmred[tid] + kmred[64 + tid] + kmred[128 + tid] + kmred[192 + tid]) * (1.0f / 64.0f);
    mxf[tid] = fmaxf(fmaxf(redmx[tid], redmx[64 + tid]),
                     fmaxf(redmx[128 + tid], redmx[192 + tid]));
    smi[tid] = 1.0f / (redsm[tid] + redsm[64 + tid] + redsm[128 + tid] + redsm[192 + tid]);
  }
  __syncthreads();   // B3: mxf/smi ready

  // ---- column pass kfm^T: thread (c=lane, g=w) owns row c, k in [16g,16g+16) ----
  {
    int c = lane, g = w;
    float e[16];
#pragma unroll
    for (int i = 0; i < 16; i++) {
      int r = g * 16 + i;
      e[i] = __expf(kcol[c * 65 + r] - mxf[r]) * smi[r];
    }
    uint4 x0 = make_uint4(pk2(e[0], e[1]), pk2(e[2], e[3]),
                          pk2(e[4], e[5]), pk2(e[6], e[7]));
    uint4 x1 = make_uint4(pk2(e[8], e[9]), pk2(e[10], e[11]),
                          pk2(e[12], e[13]), pk2(e[14], e[15]));
    *(uint4*)(kfm + c * 128 + (((2 * g) ^ (c & 7)) * 16)) = x0;
    *(uint4*)(kfm + c * 128 + (((2 * g + 1) ^ (c & 7)) * 16)) = x1;
  }
  // ---- column pass V^T: coalesced column reads -> 2 vector LDS stores ----
  {
    int c = lane, g = w;
    const float* vcol = v + (size_t)(n * 64 + g * 16) * 1024 + h * 64 + c;
    float vv[16];
#pragma unroll
    for (int i = 0; i < 16; i++) vv[i] = vcol[(size_t)i * 1024];
    uint4 x0 = make_uint4(pk2(vv[0], vv[1]), pk2(vv[2], vv[3]),
                          pk2(vv[4], vv[5]), pk2(vv[6], vv[7]));
    uint4 x1 = make_uint4(pk2(vv[8], vv[9]), pk2(vv[10], vv[11]),
                          pk2(vv[12], vv[13]), pk2(vv[14], vv[15]));
    *(uint4*)(vsl + c * 128 + (((2 * g) ^ (c & 7)) * 16)) = x0;
    *(uint4*)(vsl + c * 128 + (((2 * g + 1) ^ (c & 7)) * 16)) = x1;
  }
  __syncthreads();   // B4: kfm + vsl complete

  // ---- vT global copy (coalesced) ----
  {
    uint4* vt_out = (uint4*)(vT + ((size_t)(h * 64 + n)) * 4096);
    vt_out[tid] = ((const uint4*)vsl)[tid];
    vt_out[256 + tid] = ((const uint4*)vsl)[256 + tid];
  }
  // ---- ksum partial: wave w sums key-blocks jb=2w,2w+1 over d=lane ----
  {
    float ks = 0.f;
    short8 x0 = frag_row((const u16*)kfm, lane, 2 * w);
    short8 x1 = frag_row((const u16*)kfm, lane, 2 * w + 1);
#pragma unroll
    for (int e = 0; e < 8; e++) ks += bf2f((u16)x0[e]) + bf2f((u16)x1[e]);
    ksred[tid] = ks;
  }
  // ---- kvsum MFMA partial -> plain global store ----
  {
    f4 acc[4];
    f4 zz = {0.f, 0.f, 0.f, 0.f};
#pragma unroll
    for (int et = 0; et < 4; et++) acc[et] = zz;
#pragma unroll
    for (int ks2 = 0; ks2 < 2; ks2++) {
      short8 a_ = frag_row((const u16*)kfm, w * 16 + lq, 4 * ks2 + quad);
#pragma unroll
      for (int et = 0; et < 4; et++)
        acc[et] = MFMA_BF16(a_, frag_row((const u16*)vsl, et * 16 + lq, 4 * ks2 + quad), acc[et]);
    }
    float* kvb = kvp + ((size_t)(h * 64 + n)) * 4096;
#pragma unroll
    for (int r = 0; r < 4; r++)
#pragma unroll
      for (int et = 0; et < 4; et++)
        kvb[(w * 16 + quad * 4 + r) * 64 + et * 16 + lq] = acc[et][r];
  }
  __syncthreads();
  if (tid < 64)
    ksp[((size_t)(h * 64 + n)) * 64 + tid] = ksred[tid] + ksred[64 + tid] +
                                             ksred[128 + tid] + ksred[192 + tid];
}

// ---------------- K_B: post — reduce kvsum partials + apply W -> m2 --------
// grid 256: block (h = bx>>4, dq = bx&15) owns d-rows [dq*4, dq*4+4).
__global__ __launch_bounds__(256) void post_kernel(const float* __restrict__ kvp,
                                                   const float* __restrict__ ksp,
                                                   const float* __restrict__ wgt,
                                                   u16* __restrict__ m2t,
                                                   float* __restrict__ ksum) {
  __shared__ float kr[4][64];
  __shared__ float wl[64 * 65];   // wl[e*65 + j] = W[e][j]
  int bx = blockIdx.x, tid = threadIdx.x;
  int h = bx >> 4, dq = bx & 15;
  int j = tid & 63, rr = tid >> 6;

  // reduce kvsum row (dq*4+rr), col j over 64 n-partials
  {
    size_t off = (size_t)(dq * 4 + rr) * 64 + j;
    const float* base = kvp + (size_t)h * 64 * 4096 + off;
    float s0 = 0.f, s1 = 0.f, s2 = 0.f, s3 = 0.f;
#pragma unroll
    for (int n4 = 0; n4 < 16; n4++) {
      s0 += base[(size_t)(n4 * 4 + 0) * 4096];
      s1 += base[(size_t)(n4 * 4 + 1) * 4096];
      s2 += base[(size_t)(n4 * 4 + 2) * 4096];
      s3 += base[(size_t)(n4 * 4 + 3) * 4096];
    }
    kr[rr][j] = (s0 + s1) + (s2 + s3);
  }
  // stage W (coalesced read, conflict-free LDS)
#pragma unroll
  for (int i = 0; i < 16; i++) {
    int f = i * 256 + tid;
    wl[(f >> 6) * 65 + (f & 63)] = wgt[f];
  }
  __syncthreads();

  // m2[e][d] slice: thread (rr2 = tid>>6, e = tid&63), d = dq*4+rr2
  {
    int e = tid & 63, rr2 = tid >> 6;
    float acc = 0.f;
#pragma unroll
    for (int jj = 0; jj < 64; jj++) acc = fmaf(kr[rr2][jj], wl[e * 65 + jj], acc);
    int d = dq * 4 + rr2;
    *(u16*)((char*)m2t + (size_t)h * 8192 + e * 128 +
            (((d >> 3) ^ (e & 7)) * 16) + (d & 7) * 2) = f2bf_rne(acc);
  }
  // ksum reduction (once per h)
  if (dq == 0 && tid < 64) {
    const float* base = ksp + (size_t)h * 64 * 64 + tid;
    float s = 0.f;
#pragma unroll
    for (int n = 0; n < 64; n++) s += base[(size_t)n * 64];
    ksum[h * 64 + tid] = s;
  }
}

// ---------------- K_C: fused topk + block-sparse + linear attention --------
// grid 1024 1D, XCD-swizzled. 256 thr = 4 waves; wave w owns Q rows
// [w*16, w*16+16). Double-buffered K/V via global_load_lds: stage tile t+1
// into the idle buffer BEFORE computing tile t; one barrier/iter (its
// implicit vmcnt(0) lands after compute has hidden the load latency).
// LDS 40KB -> 4 blk/CU exact fit.
__global__ __launch_bounds__(256, 4) void fused_attn_kernel(const float* __restrict__ q,
                                                            const u16* __restrict__ kT,
                                                            const u16* __restrict__ vT,
                                                            const float* __restrict__ kmv,
                                                            const u16* __restrict__ m2t,
                                                            const float* __restrict__ ksum,
                                                            const float* __restrict__ bproj,
                                                            float* __restrict__ out) {
  __shared__ __align__(16) char smem[40960];
  // K-loop era: bufA [0,16K) {K,V} | bufB [16K,32K) {K,V} | P [32K,40K)
  // topk era:   [0,16.6K) km padded | qmp @20480 | qmf @21504
  // post-loop:  [0,8K) m2 | ksum @8192 | bias @8448
  int b = blockIdx.x;
  int m = (b >> 3) & 63;
  int h = 2 * (b & 7) + (b >> 9);
  int tid = threadIdx.x, w = tid >> 6, lane = tid & 63;
  int lq = lane & 15, quad = lane >> 4;
  char* bufA = smem;
  char* bufB = smem + 16384;
  char* p_b = smem + 32768 + w * 2048;
  float* km_s = (float*)smem;             // stride 65
  float* qmp = (float*)(smem + 20480);    // 256 floats
  float* qmf = (float*)(smem + 21504);    // 64 floats

  // ---- topk phase: q-block mean + scores vs km + butterfly top-8 ----
  {
    int c = tid & 63, g = tid >> 6;
    const float* qcol = q + ((size_t)(m * 64 + g * 16)) * 1024 + h * 64 + c;
    float qp = 0.f;
#pragma unroll
    for (int i = 0; i < 16; i++) qp += qcol[(size_t)i * 1024];
    qmp[g * 64 + c] = qp;
#pragma unroll
    for (int i = 0; i < 16; i++) {
      int idx = i * 256 + tid;
      km_s[(idx >> 6) * 65 + (idx & 63)] = kmv[h * 4096 + idx];
    }
  }
  __syncthreads();
  if (tid < 64) qmf[tid] = qmp[tid] + qmp[64 + tid] + qmp[128 + tid] + qmp[192 + tid];
  __syncthreads();
  int blks[8];
  {
    int n = lane;
    float s = 0.f;
#pragma unroll
    for (int d = 0; d < 64; d++) s += qmf[d] * km_s[n * 65 + d];
    float my = s;
#pragma unroll
    for (int t = 0; t < TSEL; t++) {
      float vv = my; int idx = n;
#pragma unroll
      for (int off = 1; off < 64; off <<= 1) {
        float ov = __shfl_xor(vv, off);
        int oi = __shfl_xor(idx, off);
        if (ov > vv || (ov == vv && oi < idx)) { vv = ov; idx = oi; }
      }
      int sel = __builtin_amdgcn_readfirstlane(idx);
      blks[t] = sel;
      if (n == sel) my = -INFINITY;
    }
  }
  __syncthreads();   // km_s dead; bufA reusable

  // ---- Q fragments straight from global (bf16 pack in-reg) ----
  const int qrow = w * 16 + lq;
  const float* qr_g = q + ((size_t)(m * 64 + qrow)) * 1024 + h * 64;
  short8 qf[2];
#pragma unroll
  for (int ks = 0; ks < 2; ks++) {
    const float* gp = qr_g + (4 * ks + quad) * 8;
    float4 a = *(const float4*)gp;
    float4 bb = *(const float4*)(gp + 4);
    u32x4 tt = {pk2(a.x, a.y), pk2(a.z, a.w), pk2(bb.x, bb.y), pk2(bb.z, bb.w)};
    qf[ks] = __builtin_bit_cast(short8, tt);
  }

  // ---- stage K/V block 0 -> bufA (async, then barrier-drain) ----
  stage_async((const char*)(kT + ((size_t)(h * 64 + blks[0])) * 4096),
              (const char*)(vT + ((size_t)(h * 64 + blks[0])) * 4096),
              bufA, w, lane);
  __syncthreads();

  float mrun = -INFINITY, lrun = 0.f;
  f4 o[4];
  f4 zz = {0.f, 0.f, 0.f, 0.f};
#pragma unroll
  for (int et = 0; et < 4; et++) o[et] = zz;

  char* cur = bufA;
  char* nxt = bufB;

  for (int t = 0; t < 8; t++) {
    // issue async stage of tile t+1 into the idle buffer (overlaps compute)
    if (t < 7)
      stage_async((const char*)(kT + ((size_t)(h * 64 + blks[t + 1])) * 4096),
                  (const char*)(vT + ((size_t)(h * 64 + blks[t + 1])) * 4096),
                  nxt, w, lane);

    const u16* kc = (const u16*)cur;
    const u16* vc = (const u16*)(cur + 8192);

    // S^T = K·Q^T
    f4 s[4];
#pragma unroll
    for (int kt = 0; kt < 4; kt++) s[kt] = zz;
    __builtin_amdgcn_s_setprio(1);
#pragma unroll
    for (int ks = 0; ks < 2; ks++)
#pragma unroll
      for (int kt = 0; kt < 4; kt++)
        s[kt] = MFMA_BF16(frag_row(kc, kt * 16 + lq, 4 * ks + quad), qf[ks], s[kt]);
    __builtin_amdgcn_s_setprio(0);

    // online softmax (16 scores/lane), P row lq -> wave-private slab
    float mp = -INFINITY;
#pragma unroll
    for (int kt = 0; kt < 4; kt++)
#pragma unroll
      for (int r = 0; r < 4; r++) mp = fmaxf(mp, s[kt][r]);
    mp = fmaxf(mp, __shfl_xor(mp, 16));
    mp = fmaxf(mp, __shfl_xor(mp, 32));
    mp *= 0.125f;
    // exact defer: lut is score-descending, so later tiles rarely raise the
    // max -> skip the rescale pass entirely when no lane's max grows.
    if (__any(mp > mrun)) {
      float mn = fmaxf(mrun, mp);
      float al = __expf(mrun - mn);
      mrun = mn;
      lrun *= al;
#pragma unroll
      for (int et = 0; et < 4; et++)
#pragma unroll
        for (int r = 0; r < 4; r++) o[et][r] *= al;
    }
    float rs_ = 0.f;
#pragma unroll
    for (int kt = 0; kt < 4; kt++) {
      float p0 = __expf(fmaf(s[kt][0], 0.125f, -mrun));
      float p1 = __expf(fmaf(s[kt][1], 0.125f, -mrun));
      float p2 = __expf(fmaf(s[kt][2], 0.125f, -mrun));
      float p3 = __expf(fmaf(s[kt][3], 0.125f, -mrun));
      rs_ += p0 + p1 + p2 + p3;
      u32 lo32 = (__float_as_uint(p0) >> 16) | (__float_as_uint(p1) & 0xffff0000u);
      u32 hi32 = (__float_as_uint(p2) >> 16) | (__float_as_uint(p3) & 0xffff0000u);
      int addr = lq * 128 + (((kt * 2 + (quad >> 1)) ^ (lq & 7)) * 16) + (quad & 1) * 8;
      *(uint2*)(p_b + addr) = make_uint2(lo32, hi32);
    }
    rs_ += __shfl_xor(rs_, 16);
    rs_ += __shfl_xor(rs_, 32);
    lrun += rs_;

    // O^T += V^T · P^T
    __builtin_amdgcn_s_setprio(1);
#pragma unroll
    for (int ks = 0; ks < 2; ks++) {
      short8 pf = frag_row((const u16*)p_b, lq, 4 * ks + quad);
#pragma unroll
      for (int et = 0; et < 4; et++)
        o[et] = MFMA_BF16(frag_row(vc, et * 16 + lq, 4 * ks + quad), pf, o[et]);
    }
    __builtin_amdgcn_s_setprio(0);

    // one barrier: drains this iter's stage (vmcnt) + all reads of cur done
    __syncthreads();
    char* tmp = cur; cur = nxt; nxt = tmp;
  }

  // ---- stage m2 + ksum + bias into smem (reuse), then fused linear attn ----
  {
    const uint4* src = (const uint4*)((const char*)m2t + (size_t)h * 8192);
    ((uint4*)smem)[tid] = src[tid];
    ((uint4*)smem)[256 + tid] = src[256 + tid];
    if (tid < 64) {
      ((float*)(smem + 8192))[tid] = ksum[h * 64 + tid];
      ((float*)(smem + 8448))[tid] = bproj[tid];
    }
  }
  __syncthreads();
  u16* m2_l = (u16*)smem;
  float* ks_s = (float*)(smem + 8192);
  float* b_s = (float*)(smem + 8448);

  // linear-attn feature map from fp32 q row (cols quad*16..+16)
  float ev[16];
  float mx = -INFINITY;
#pragma unroll
  for (int c4 = 0; c4 < 4; c4++) {
    float4 a = *(const float4*)(qr_g + quad * 16 + c4 * 4);
    ev[c4 * 4] = a.x; ev[c4 * 4 + 1] = a.y; ev[c4 * 4 + 2] = a.z; ev[c4 * 4 + 3] = a.w;
    mx = fmaxf(mx, fmaxf(fmaxf(a.x, a.y), fmaxf(a.z, a.w)));
  }
  mx = fmaxf(mx, __shfl_xor(mx, 16));
  mx = fmaxf(mx, __shfl_xor(mx, 32));
  float sum = 0.f, eks = 0.f;
#pragma unroll
  for (int j = 0; j < 16; j++) {
    float e = __expf(ev[j] - mx);
    ev[j] = e;
    sum += e;
    eks += e * ks_s[quad * 16 + j];
  }
  sum += __shfl_xor(sum, 16); sum += __shfl_xor(sum, 32);
  eks += __shfl_xor(eks, 16); eks += __shfl_xor(eks, 32);
  float invs = 1.0f / sum;
  float den = fmaf(eks, invs, 1e-6f);
  float scale = invs / den;
  // E row lq -> wave slab (blocks 2*quad, 2*quad+1)
  uint4 e0v = make_uint4(pk2(ev[0], ev[1]), pk2(ev[2], ev[3]),
                         pk2(ev[4], ev[5]), pk2(ev[6], ev[7]));
  uint4 e1v = make_uint4(pk2(ev[8], ev[9]), pk2(ev[10], ev[11]),
                         pk2(ev[12], ev[13]), pk2(ev[14], ev[15]));
  *(uint4*)(p_b + lq * 128 + (((2 * quad) ^ (lq & 7)) * 16)) = e0v;
  *(uint4*)(p_b + lq * 128 + (((2 * quad + 1) ^ (lq & 7)) * 16)) = e1v;

  f4 oc[4];
  f4 zz2 = {0.f, 0.f, 0.f, 0.f};
#pragma unroll
  for (int et = 0; et < 4; et++) oc[et] = zz2;
  __builtin_amdgcn_s_setprio(1);
#pragma unroll
  for (int ks2 = 0; ks2 < 2; ks2++) {
    short8 ef = frag_row((const u16*)p_b, lq, 4 * ks2 + quad);
#pragma unroll
    for (int et = 0; et < 4; et++)
      oc[et] = MFMA_BF16(frag_row(m2_l, et * 16 + lq, 4 * ks2 + quad), ef, oc[et]);
  }
  __builtin_amdgcn_s_setprio(0);

  // ---- single write: out = o_s/l + o_l*scale + bias ----
  float invl = 1.0f / lrun;
  float* gp = out + ((size_t)(m * 64 + qrow)) * 1024 + h * 64 + quad * 4;
#pragma unroll
  for (int et = 0; et < 4; et++) {
    int e0 = et * 16 + quad * 4;
    float4 ov;
    ov.x = o[et][0] * invl + oc[et][0] * scale + b_s[e0 + 0];
    ov.y = o[et][1] * invl + oc[et][1] * scale + b_s[e0 + 1];
    ov.z = o[et][2] * invl + oc[et][2] * scale + b_s[e0 + 2];
    ov.w = o[et][3] * invl + oc[et][3] * scale + b_s[e0 + 3];
    *(float4*)(gp + et * 16) = ov;
  }
}

extern "C" void kernel_launch(void* const* d_in, const int* in_sizes, int n_in,
                              void* d_out, int out_size, void* d_ws, size_t ws_size,
                              hipStream_t stream) {
  const float* q = (const float*)d_in[0];
  const float* k = (const float*)d_in[1];
  const float* v = (const float*)d_in[2];
  const float* w = (const float*)d_in[3];
  const float* b = (const float*)d_in[4];
  float* out = (float*)d_out;

  // ws: kT 8MB u16 | vT 8MB u16 | kvp 16MB f32 | ksp 256KB f32 |
  //     kmv 256KB f32 | ksum 4KB f32 | m2t 128KB u16   (~32.6MB of 256MB)
  u16* kT = (u16*)d_ws;
  u16* vT = kT + 4194304;
  float* kvp = (float*)(vT + 4194304);
  float* ksp = kvp + 4194304;
  float* kmv = ksp + 65536;
  float* ksum = kmv + 65536;
  u16* m2t = (u16*)(ksum + 1024);

  prep_kernel<<<1024, 256, 0, stream>>>(k, v, kT, vT, kvp, ksp, kmv);
  post_kernel<<<256, 256, 0, stream>>>(kvp, ksp, w, m2t, ksum);
  fused_attn_kernel<<<1024, 256, 0, stream>>>(q, kT, vT, kmv, m2t, ksum, b, out);
}

// Round 10
// 130.110 us; speedup vs baseline: 7.0460x; 1.0134x over previous
//
#include <hip/hip_runtime.h>

// SparseLinearAttention: B=1, L=4096, H=16, D=64, BLKQ=BLKK=64, M=N=64, T=8.
// fp32 I/O. 3 dispatches (R2 skeleton; R7 lesson: no intra-kernel handoff):
//   prep: column-pass transposes; kT now staged in LDS (vsl reuse) and
//         copied out LINEARLY (was a 64-line global scatter).
// -> post (reduce kvp + apply W)  [unchanged]
// -> fused attn: double-buffered K/V via global_load_lds; t==7's idle
//    prefetch slot stages m2/ksum/bias into nxt (post-loop stage deleted).

#define NH   16
#define DH   64
#define NBLK 64
#define TSEL 8

typedef unsigned short u16;
typedef unsigned int   u32;
typedef __attribute__((ext_vector_type(8))) short short8;  // 8 bf16
typedef __attribute__((ext_vector_type(4))) float f4;
typedef __attribute__((ext_vector_type(4))) u32 u32x4;

#define MFMA_BF16(a, b, c) __builtin_amdgcn_mfma_f32_16x16x32_bf16(a, b, c, 0, 0, 0)

__device__ __forceinline__ u16 f2bf_rne(float f) {
  u32 u = __float_as_uint(f);
  u += 0x7fffu + ((u >> 16) & 1u);
  return (u16)(u >> 16);
}
__device__ __forceinline__ u32 pk2(float a, float b) {
  return (u32)f2bf_rne(a) | ((u32)f2bf_rne(b) << 16);
}
__device__ __forceinline__ float bf2f(u16 u) { return __uint_as_float(((u32)u) << 16); }

// 8-bf16 fragment from a swizzled row-major bf16 tile (128B rows; logical
// 16B block j of row r stored at j^(r&7)).
__device__ __forceinline__ short8 frag_row(const u16* t, int row, int jblk) {
  return *(const short8*)((const char*)t + row * 128 + ((jblk ^ (row & 7)) * 16));
}

// async global->LDS, 16B per lane (wave-uniform base + lane*16 layout).
__device__ __forceinline__ void gload_lds16(const char* g, char* l) {
  __builtin_amdgcn_global_load_lds(
      (const __attribute__((address_space(1))) char*)g,
      (__attribute__((address_space(3))) char*)l, 16, 0, 0);
}

// stage one K/V tile pair (8KB + 8KB) into dst (K@0, V@8192).
// wave 0: K[0,4K) w1: K[4K,8K) w2: V[0,4K) w3: V[4K,8K); 4 x 1KB insts each.
__device__ __forceinline__ void stage_async(const char* ktb, const char* vtb,
                                            char* dst, int w, int lane) {
  const char* s = ((w & 2) ? vtb : ktb) + (w & 1) * 4096 + lane * 16;
  char* d = dst + ((w & 2) ? 8192 : 0) + (w & 1) * 4096 + lane * 16;
#pragma unroll
  for (int i = 0; i < 4; i++) gload_lds16(s + i * 1024, d + i * 1024);
}

// stage m2 (8KB, waves 0-1) + ksum (256B) + bias (256B) (wave 2, lanes<32).
__device__ __forceinline__ void stage_m2(const char* m2b, const float* ksum_h,
                                         const float* bproj, char* dst,
                                         int w, int lane) {
  if (w < 2) {
    const char* s = m2b + w * 4096 + lane * 16;
    char* d = dst + w * 4096 + lane * 16;
#pragma unroll
    for (int i = 0; i < 4; i++) gload_lds16(s + i * 1024, d + i * 1024);
  } else if (w == 2 && lane < 32) {
    const char* s = (lane < 16) ? ((const char*)ksum_h + lane * 16)
                                : ((const char*)bproj + (lane - 16) * 16);
    gload_lds16(s, dst + 8192 + lane * 16);
  }
}

// ---------------- K_A: one-pass prep over K/V (column-pass transposes) -----
// grid 1024 (XCD-swizzled: h = 2*(b&7) + (b>>9), n = (b>>3)&63), 256 thr.
__global__ __launch_bounds__(256) void prep_kernel(const float* __restrict__ k,
                                                   const float* __restrict__ v,
                                                   u16* __restrict__ kT,
                                                   u16* __restrict__ vT,
                                                   float* __restrict__ kvp,
                                                   float* __restrict__ ksp,
                                                   float* __restrict__ kmv) {
  __shared__ __align__(16) char vsl[8192];    // kT staging pre-B3, V^T after
  __shared__ __align__(16) char kfm[8192];    // kfm^T bf16 swizzled
  __shared__ float kcol[64 * 65];             // raw K, column-major
  __shared__ float redmx[256];
  __shared__ float redsm[256];
  __shared__ float kmred[256];
  __shared__ float ksred[256];
  __shared__ float mxf[64];                   // folded row max
  __shared__ float smi[64];                   // folded 1/rowsum
  int b = blockIdx.x;
  int n = (b >> 3) & 63;
  int h = 2 * (b & 7) + (b >> 9);
  int tid = threadIdx.x;
  int w = tid >> 6, lane = tid & 63;
  int row = lane, qd = w;
  int lq = lane & 15, quad = lane >> 4;

  // ---- K row segment (16 floats), coalesced ----
  float kv[16];
  {
    const float* kr = k + (size_t)(n * 64 + row) * 1024 + h * 64 + qd * 16;
#pragma unroll
    for (int c4 = 0; c4 < 4; c4++) {
      float4 a = *(const float4*)(kr + c4 * 4);
      kv[c4 * 4] = a.x; kv[c4 * 4 + 1] = a.y; kv[c4 * 4 + 2] = a.z; kv[c4 * 4 + 3] = a.w;
    }
  }
  // ---- kT tile into LDS (vsl reuse; swizzled row layout) ----
  {
    uint4 w0 = make_uint4(pk2(kv[0], kv[1]), pk2(kv[2], kv[3]),
                          pk2(kv[4], kv[5]), pk2(kv[6], kv[7]));
    uint4 w1 = make_uint4(pk2(kv[8], kv[9]), pk2(kv[10], kv[11]),
                          pk2(kv[12], kv[13]), pk2(kv[14], kv[15]));
    *(uint4*)(vsl + row * 128 + (((2 * qd) ^ (row & 7)) * 16)) = w0;
    *(uint4*)(vsl + row * 128 + (((2 * qd + 1) ^ (row & 7)) * 16)) = w1;
  }
  // ---- raw K into column-major LDS ----
  {
#pragma unroll
    for (int j = 0; j < 16; j++) kcol[(qd * 16 + j) * 65 + row] = kv[j];
  }
  // ---- row max partial ----
  {
    float mx = kv[0];
#pragma unroll
    for (int j = 1; j < 16; j++) mx = fmaxf(mx, kv[j]);
    redmx[qd * 64 + row] = mx;
  }
  __syncthreads();   // B1: vsl(kT) + kcol + redmx ready

  // ---- kT copy-out (linear, coalesced) ----
  {
    uint4* kt_out = (uint4*)(kT + ((size_t)(h * 64 + n)) * 4096);
    kt_out[tid] = ((const uint4*)vsl)[tid];
    kt_out[256 + tid] = ((const uint4*)vsl)[256 + tid];
  }
  // ---- km partials ----
  {
    int c = tid & 63, g = tid >> 6;
    float pk = 0.f;
#pragma unroll
    for (int i = 0; i < 16; i++) pk += kcol[c * 65 + g * 16 + i];
    kmred[g * 64 + c] = pk;
  }
  // ---- row pass: max fold + exp-sum partial (exps not kept) ----
  {
    float mx = fmaxf(fmaxf(redmx[row], redmx[64 + row]),
                     fmaxf(redmx[128 + row], redmx[192 + row]));
    float sm = 0.f;
#pragma unroll
    for (int j = 0; j < 16; j++) sm += __expf(kv[j] - mx);
    redsm[qd * 64 + row] = sm;
  }
  __syncthreads();   // B2: kmred + redsm ready; vsl reads done
  if (tid < 64) {
    kmv[h * 4096 + n * 64 + tid] =
        (kmred[tid] + kmred[64 + tid] + kmred[128 + tid] + kmred[192 + tid]) * (1.0f / 64.0f);
    mxf[tid] = fmaxf(fmaxf(redmx[tid], redmx[64 + tid]),
                     fmaxf(redmx[128 + tid], redmx[192 + tid]));
    smi[tid] = 1.0f / (redsm[tid] + redsm[64 + tid] + redsm[128 + tid] + redsm[192 + tid]);
  }
  __syncthreads();   // B3: mxf/smi ready

  // ---- column pass kfm^T: thread (c=lane, g=w) owns row c, k in [16g,16g+16) ----
  {
    int c = lane, g = w;
    float e[16];
#pragma unroll
    for (int i = 0; i < 16; i++) {
      int r = g * 16 + i;
      e[i] = __expf(kcol[c * 65 + r] - mxf[r]) * smi[r];
    }
    uint4 x0 = make_uint4(pk2(e[0], e[1]), pk2(e[2], e[3]),
                          pk2(e[4], e[5]), pk2(e[6], e[7]));
    uint4 x1 = make_uint4(pk2(e[8], e[9]), pk2(e[10], e[11]),
                          pk2(e[12], e[13]), pk2(e[14], e[15]));
    *(uint4*)(kfm + c * 128 + (((2 * g) ^ (c & 7)) * 16)) = x0;
    *(uint4*)(kfm + c * 128 + (((2 * g + 1) ^ (c & 7)) * 16)) = x1;
  }
  // ---- column pass V^T: coalesced column reads -> 2 vector LDS stores ----
  {
    int c = lane, g = w;
    const float* vcol = v + (size_t)(n * 64 + g * 16) * 1024 + h * 64 + c;
    float vv[16];
#pragma unroll
    for (int i = 0; i < 16; i++) vv[i] = vcol[(size_t)i * 1024];
    uint4 x0 = make_uint4(pk2(vv[0], vv[1]), pk2(vv[2], vv[3]),
                          pk2(vv[4], vv[5]), pk2(vv[6], vv[7]));
    uint4 x1 = make_uint4(pk2(vv[8], vv[9]), pk2(vv[10], vv[11]),
                          pk2(vv[12], vv[13]), pk2(vv[14], vv[15]));
    *(uint4*)(vsl + c * 128 + (((2 * g) ^ (c & 7)) * 16)) = x0;
    *(uint4*)(vsl + c * 128 + (((2 * g + 1) ^ (c & 7)) * 16)) = x1;
  }
  __syncthreads();   // B4: kfm + vsl(V^T) complete

  // ---- vT global copy (coalesced) ----
  {
    uint4* vt_out = (uint4*)(vT + ((size_t)(h * 64 + n)) * 4096);
    vt_out[tid] = ((const uint4*)vsl)[tid];
    vt_out[256 + tid] = ((const uint4*)vsl)[256 + tid];
  }
  // ---- ksum partial: wave w sums key-blocks jb=2w,2w+1 over d=lane ----
  {
    float ks = 0.f;
    short8 x0 = frag_row((const u16*)kfm, lane, 2 * w);
    short8 x1 = frag_row((const u16*)kfm, lane, 2 * w + 1);
#pragma unroll
    for (int e = 0; e < 8; e++) ks += bf2f((u16)x0[e]) + bf2f((u16)x1[e]);
    ksred[tid] = ks;
  }
  // ---- kvsum MFMA partial -> plain global store ----
  {
    f4 acc[4];
    f4 zz = {0.f, 0.f, 0.f, 0.f};
#pragma unroll
    for (int et = 0; et < 4; et++) acc[et] = zz;
#pragma unroll
    for (int ks2 = 0; ks2 < 2; ks2++) {
      short8 a_ = frag_row((const u16*)kfm, w * 16 + lq, 4 * ks2 + quad);
#pragma unroll
      for (int et = 0; et < 4; et++)
        acc[et] = MFMA_BF16(a_, frag_row((const u16*)vsl, et * 16 + lq, 4 * ks2 + quad), acc[et]);
    }
    float* kvb = kvp + ((size_t)(h * 64 + n)) * 4096;
#pragma unroll
    for (int r = 0; r < 4; r++)
#pragma unroll
      for (int et = 0; et < 4; et++)
        kvb[(w * 16 + quad * 4 + r) * 64 + et * 16 + lq] = acc[et][r];
  }
  __syncthreads();
  if (tid < 64)
    ksp[((size_t)(h * 64 + n)) * 64 + tid] = ksred[tid] + ksred[64 + tid] +
                                             ksred[128 + tid] + ksred[192 + tid];
}

// ---------------- K_B: post — reduce kvsum partials + apply W -> m2 --------
// grid 256: block (h = bx>>4, dq = bx&15) owns d-rows [dq*4, dq*4+4).
__global__ __launch_bounds__(256) void post_kernel(const float* __restrict__ kvp,
                                                   const float* __restrict__ ksp,
                                                   const float* __restrict__ wgt,
                                                   u16* __restrict__ m2t,
                                                   float* __restrict__ ksum) {
  __shared__ float kr[4][64];
  __shared__ float wl[64 * 65];   // wl[e*65 + j] = W[e][j]
  int bx = blockIdx.x, tid = threadIdx.x;
  int h = bx >> 4, dq = bx & 15;
  int j = tid & 63, rr = tid >> 6;

  // reduce kvsum row (dq*4+rr), col j over 64 n-partials
  {
    size_t off = (size_t)(dq * 4 + rr) * 64 + j;
    const float* base = kvp + (size_t)h * 64 * 4096 + off;
    float s0 = 0.f, s1 = 0.f, s2 = 0.f, s3 = 0.f;
#pragma unroll
    for (int n4 = 0; n4 < 16; n4++) {
      s0 += base[(size_t)(n4 * 4 + 0) * 4096];
      s1 += base[(size_t)(n4 * 4 + 1) * 4096];
      s2 += base[(size_t)(n4 * 4 + 2) * 4096];
      s3 += base[(size_t)(n4 * 4 + 3) * 4096];
    }
    kr[rr][j] = (s0 + s1) + (s2 + s3);
  }
  // stage W (coalesced read, conflict-free LDS)
#pragma unroll
  for (int i = 0; i < 16; i++) {
    int f = i * 256 + tid;
    wl[(f >> 6) * 65 + (f & 63)] = wgt[f];
  }
  __syncthreads();

  // m2[e][d] slice: thread (rr2 = tid>>6, e = tid&63), d = dq*4+rr2
  {
    int e = tid & 63, rr2 = tid >> 6;
    float acc = 0.f;
#pragma unroll
    for (int jj = 0; jj < 64; jj++) acc = fmaf(kr[rr2][jj], wl[e * 65 + jj], acc);
    int d = dq * 4 + rr2;
    *(u16*)((char*)m2t + (size_t)h * 8192 + e * 128 +
            (((d >> 3) ^ (e & 7)) * 16) + (d & 7) * 2) = f2bf_rne(acc);
  }
  // ksum reduction (once per h)
  if (dq == 0 && tid < 64) {
    const float* base = ksp + (size_t)h * 64 * 64 + tid;
    float s = 0.f;
#pragma unroll
    for (int n = 0; n < 64; n++) s += base[(size_t)n * 64];
    ksum[h * 64 + tid] = s;
  }
}

// ---------------- K_C: fused topk + block-sparse + linear attention --------
// grid 1024 1D, XCD-swizzled. 256 thr = 4 waves; wave w owns Q rows
// [w*16, w*16+16). Double-buffered K/V via global_load_lds; t==7 stages
// m2/ksum/bias into nxt (its prefetch slot is idle), so the linear part
// starts immediately after the loop's final barrier. 40KB LDS -> 4 blk/CU.
__global__ __launch_bounds__(256, 4) void fused_attn_kernel(const float* __restrict__ q,
                                                            const u16* __restrict__ kT,
                                                            const u16* __restrict__ vT,
                                                            const float* __restrict__ kmv,
                                                            const u16* __restrict__ m2t,
                                                            const float* __restrict__ ksum,
                                                            const float* __restrict__ bproj,
                                                            float* __restrict__ out) {
  __shared__ __align__(16) char smem[40960];
  // K-loop era: bufA [0,16K) {K,V} | bufB [16K,32K) {K,V} | P [32K,40K)
  // topk era:   [0,16.6K) km padded | qmp @20480 | qmf @21504
  // post-loop:  cur holds m2 @0 | ksum @8192 | bias @8448
  int b = blockIdx.x;
  int m = (b >> 3) & 63;
  int h = 2 * (b & 7) + (b >> 9);
  int tid = threadIdx.x, w = tid >> 6, lane = tid & 63;
  int lq = lane & 15, quad = lane >> 4;
  char* bufA = smem;
  char* bufB = smem + 16384;
  char* p_b = smem + 32768 + w * 2048;
  float* km_s = (float*)smem;             // stride 65
  float* qmp = (float*)(smem + 20480);    // 256 floats
  float* qmf = (float*)(smem + 21504);    // 64 floats

  // ---- topk phase: q-block mean + scores vs km + butterfly top-8 ----
  {
    int c = tid & 63, g = tid >> 6;
    const float* qcol = q + ((size_t)(m * 64 + g * 16)) * 1024 + h * 64 + c;
    float qp = 0.f;
#pragma unroll
    for (int i = 0; i < 16; i++) qp += qcol[(size_t)i * 1024];
    qmp[g * 64 + c] = qp;
#pragma unroll
    for (int i = 0; i < 16; i++) {
      int idx = i * 256 + tid;
      km_s[(idx >> 6) * 65 + (idx & 63)] = kmv[h * 4096 + idx];
    }
  }
  __syncthreads();
  if (tid < 64) qmf[tid] = qmp[tid] + qmp[64 + tid] + qmp[128 + tid] + qmp[192 + tid];
  __syncthreads();
  int blks[8];
  {
    int n = lane;
    float s = 0.f;
#pragma unroll
    for (int d = 0; d < 64; d++) s += qmf[d] * km_s[n * 65 + d];
    float my = s;
#pragma unroll
    for (int t = 0; t < TSEL; t++) {
      float vv = my; int idx = n;
#pragma unroll
      for (int off = 1; off < 64; off <<= 1) {
        float ov = __shfl_xor(vv, off);
        int oi = __shfl_xor(idx, off);
        if (ov > vv || (ov == vv && oi < idx)) { vv = ov; idx = oi; }
      }
      int sel = __builtin_amdgcn_readfirstlane(idx);
      blks[t] = sel;
      if (n == sel) my = -INFINITY;
    }
  }
  __syncthreads();   // km_s dead; bufA reusable

  // ---- Q fragments straight from global (bf16 pack in-reg) ----
  const int qrow = w * 16 + lq;
  const float* qr_g = q + ((size_t)(m * 64 + qrow)) * 1024 + h * 64;
  short8 qf[2];
#pragma unroll
  for (int ks = 0; ks < 2; ks++) {
    const float* gp = qr_g + (4 * ks + quad) * 8;
    float4 a = *(const float4*)gp;
    float4 bb = *(const float4*)(gp + 4);
    u32x4 tt = {pk2(a.x, a.y), pk2(a.z, a.w), pk2(bb.x, bb.y), pk2(bb.z, bb.w)};
    qf[ks] = __builtin_bit_cast(short8, tt);
  }

  // ---- stage K/V block 0 -> bufA (async, then barrier-drain) ----
  stage_async((const char*)(kT + ((size_t)(h * 64 + blks[0])) * 4096),
              (const char*)(vT + ((size_t)(h * 64 + blks[0])) * 4096),
              bufA, w, lane);
  __syncthreads();

  float mrun = -INFINITY, lrun = 0.f;
  f4 o[4];
  f4 zz = {0.f, 0.f, 0.f, 0.f};
#pragma unroll
  for (int et = 0; et < 4; et++) o[et] = zz;

  char* cur = bufA;
  char* nxt = bufB;

  for (int t = 0; t < 8; t++) {
    // issue async stage into the idle buffer (overlaps compute):
    // tiles 1..7 for t<7; m2/ksum/bias for the final iteration.
    if (t < 7)
      stage_async((const char*)(kT + ((size_t)(h * 64 + blks[t + 1])) * 4096),
                  (const char*)(vT + ((size_t)(h * 64 + blks[t + 1])) * 4096),
                  nxt, w, lane);
    else
      stage_m2((const char*)m2t + (size_t)h * 8192, ksum + h * 64, bproj,
               nxt, w, lane);

    const u16* kc = (const u16*)cur;
    const u16* vc = (const u16*)(cur + 8192);

    // S^T = K·Q^T
    f4 s[4];
#pragma unroll
    for (int kt = 0; kt < 4; kt++) s[kt] = zz;
    __builtin_amdgcn_s_setprio(1);
#pragma unroll
    for (int ks = 0; ks < 2; ks++)
#pragma unroll
      for (int kt = 0; kt < 4; kt++)
        s[kt] = MFMA_BF16(frag_row(kc, kt * 16 + lq, 4 * ks + quad), qf[ks], s[kt]);
    __builtin_amdgcn_s_setprio(0);

    // online softmax (16 scores/lane), P row lq -> wave-private slab
    float mp = -INFINITY;
#pragma unroll
    for (int kt = 0; kt < 4; kt++)
#pragma unroll
      for (int r = 0; r < 4; r++) mp = fmaxf(mp, s[kt][r]);
    mp = fmaxf(mp, __shfl_xor(mp, 16));
    mp = fmaxf(mp, __shfl_xor(mp, 32));
    mp *= 0.125f;
    // exact defer: lut is score-descending, so later tiles rarely raise the
    // max -> skip the rescale pass entirely when no lane's max grows.
    if (__any(mp > mrun)) {
      float mn = fmaxf(mrun, mp);
      float al = __expf(mrun - mn);
      mrun = mn;
      lrun *= al;
#pragma unroll
      for (int et = 0; et < 4; et++)
#pragma unroll
        for (int r = 0; r < 4; r++) o[et][r] *= al;
    }
    float rs_ = 0.f;
#pragma unroll
    for (int kt = 0; kt < 4; kt++) {
      float p0 = __expf(fmaf(s[kt][0], 0.125f, -mrun));
      float p1 = __expf(fmaf(s[kt][1], 0.125f, -mrun));
      float p2 = __expf(fmaf(s[kt][2], 0.125f, -mrun));
      float p3 = __expf(fmaf(s[kt][3], 0.125f, -mrun));
      rs_ += p0 + p1 + p2 + p3;
      u32 lo32 = (__float_as_uint(p0) >> 16) | (__float_as_uint(p1) & 0xffff0000u);
      u32 hi32 = (__float_as_uint(p2) >> 16) | (__float_as_uint(p3) & 0xffff0000u);
      int addr = lq * 128 + (((kt * 2 + (quad >> 1)) ^ (lq & 7)) * 16) + (quad & 1) * 8;
      *(uint2*)(p_b + addr) = make_uint2(lo32, hi32);
    }
    rs_ += __shfl_xor(rs_, 16);
    rs_ += __shfl_xor(rs_, 32);
    lrun += rs_;

    // O^T += V^T · P^T
    __builtin_amdgcn_s_setprio(1);
#pragma unroll
    for (int ks = 0; ks < 2; ks++) {
      short8 pf = frag_row((const u16*)p_b, lq, 4 * ks + quad);
#pragma unroll
      for (int et = 0; et < 4; et++)
        o[et] = MFMA_BF16(frag_row(vc, et * 16 + lq, 4 * ks + quad), pf, o[et]);
    }
    __builtin_amdgcn_s_setprio(0);

    // one barrier: drains this iter's stage (vmcnt) + all reads of cur done
    __syncthreads();
    char* tmp = cur; cur = nxt; nxt = tmp;
  }

  // cur now holds m2 @0 | ksum @8192 | bias @8448 (staged at t==7)
  u16* m2_l = (u16*)cur;
  float* ks_s = (float*)(cur + 8192);
  float* b_s = (float*)(cur + 8448);

  // linear-attn feature map from fp32 q row (cols quad*16..+16)
  float ev[16];
  float mx = -INFINITY;
#pragma unroll
  for (int c4 = 0; c4 < 4; c4++) {
    float4 a = *(const float4*)(qr_g + quad * 16 + c4 * 4);
    ev[c4 * 4] = a.x; ev[c4 * 4 + 1] = a.y; ev[c4 * 4 + 2] = a.z; ev[c4 * 4 + 3] = a.w;
    mx = fmaxf(mx, fmaxf(fmaxf(a.x, a.y), fmaxf(a.z, a.w)));
  }
  mx = fmaxf(mx, __shfl_xor(mx, 16));
  mx = fmaxf(mx, __shfl_xor(mx, 32));
  float sum = 0.f, eks = 0.f;
#pragma unroll
  for (int j = 0; j < 16; j++) {
    float e = __expf(ev[j] - mx);
    ev[j] = e;
    sum += e;
    eks += e * ks_s[quad * 16 + j];
  }
  sum += __shfl_xor(sum, 16); sum += __shfl_xor(sum, 32);
  eks += __shfl_xor(eks, 16); eks += __shfl_xor(eks, 32);
  float invs = 1.0f / sum;
  float den = fmaf(eks, invs, 1e-6f);
  float scale = invs / den;
  // E row lq -> wave slab (blocks 2*quad, 2*quad+1)
  uint4 e0v = make_uint4(pk2(ev[0], ev[1]), pk2(ev[2], ev[3]),
                         pk2(ev[4], ev[5]), pk2(ev[6], ev[7]));
  uint4 e1v = make_uint4(pk2(ev[8], ev[9]), pk2(ev[10], ev[11]),
                         pk2(ev[12], ev[13]), pk2(ev[14], ev[15]));
  *(uint4*)(p_b + lq * 128 + (((2 * quad) ^ (lq & 7)) * 16)) = e0v;
  *(uint4*)(p_b + lq * 128 + (((2 * quad + 1) ^ (lq & 7)) * 16)) = e1v;

  f4 oc[4];
  f4 zz2 = {0.f, 0.f, 0.f, 0.f};
#pragma unroll
  for (int et = 0; et < 4; et++) oc[et] = zz2;
  __builtin_amdgcn_s_setprio(1);
#pragma unroll
  for (int ks2 = 0; ks2 < 2; ks2++) {
    short8 ef = frag_row((const u16*)p_b, lq, 4 * ks2 + quad);
#pragma unroll
    for (int et = 0; et < 4; et++)
      oc[et] = MFMA_BF16(frag_row(m2_l, et * 16 + lq, 4 * ks2 + quad), ef, oc[et]);
  }
  __builtin_amdgcn_s_setprio(0);

  // ---- single write: out = o_s/l + o_l*scale + bias ----
  float invl = 1.0f / lrun;
  float* gp = out + ((size_t)(m * 64 + qrow)) * 1024 + h * 64 + quad * 4;
#pragma unroll
  for (int et = 0; et < 4; et++) {
    int e0 = et * 16 + quad * 4;
    float4 ov;
    ov.x = o[et][0] * invl + oc[et][0] * scale + b_s[e0 + 0];
    ov.y = o[et][1] * invl + oc[et][1] * scale + b_s[e0 + 1];
    ov.z = o[et][2] * invl + oc[et][2] * scale + b_s[e0 + 2];
    ov.w = o[et][3] * invl + oc[et][3] * scale + b_s[e0 + 3];
    *(float4*)(gp + et * 16) = ov;
  }
}

extern "C" void kernel_launch(void* const* d_in, const int* in_sizes, int n_in,
                              void* d_out, int out_size, void* d_ws, size_t ws_size,
                              hipStream_t stream) {
  const float* q = (const float*)d_in[0];
  const float* k = (const float*)d_in[1];
  const float* v = (const float*)d_in[2];
  const float* w = (const float*)d_in[3];
  const float* b = (const float*)d_in[4];
  float* out = (float*)d_out;

  // ws: kT 8MB u16 | vT 8MB u16 | kvp 16MB f32 | ksp 256KB f32 |
  //     kmv 256KB f32 | ksum 4KB f32 | m2t 128KB u16   (~32.6MB of 256MB)
  u16* kT = (u16*)d_ws;
  u16* vT = kT + 4194304;
  float* kvp = (float*)(vT + 4194304);
  float* ksp = kvp + 4194304;
  float* kmv = ksp + 65536;
  float* ksum = kmv + 65536;
  u16* m2t = (u16*)(ksum + 1024);

  prep_kernel<<<1024, 256, 0, stream>>>(k, v, kT, vT, kvp, ksp, kmv);
  post_kernel<<<256, 256, 0, stream>>>(kvp, ksp, w, m2t, ksum);
  fused_attn_kernel<<<1024, 256, 0, stream>>>(q, kT, vT, kmv, m2t, ksum, b, out);
}